// Round 8
// baseline (1058.567 us; speedup 1.0000x reference)
//
#include <hip/hip_runtime.h>
#include <hip/hip_bf16.h>

#define Bn   4
#define Cn   512
#define Hn   768
#define NHn  12
#define NEn  20
#define MMn  23
#define Pn   380
#define Mr   1520     // B*P
#define QSn  128
#define NEGV (-10000.0f)
#define SCL  0.036084391824351615f   // 1/sqrt(768)

typedef unsigned int uint32;
typedef __attribute__((ext_vector_type(4))) float float4v;
typedef __attribute__((ext_vector_type(2))) _Float16 half2v;
typedef __attribute__((ext_vector_type(2))) __fp16 fp16x2;
typedef __attribute__((ext_vector_type(8))) _Float16 half8;

// f32 -> f16 single element (RNE, v_cvt_f16_f32)
__device__ __forceinline__ unsigned short f2h(float f){
    return __builtin_bit_cast(unsigned short, (_Float16)f);
}
// pack 2 f32 -> 2 f16 in one v_cvt_pkrtz_f16_f32
__device__ __forceinline__ uint32 pkrtz(float a, float b){
    fp16x2 h = __builtin_amdgcn_cvt_pkrtz(a, b);
    return __builtin_bit_cast(uint32, h);
}
// half8 * splat(half2) elementwise -> 4x v_pk_mul_f16
__device__ __forceinline__ half8 mulsplat(half8 a, uint32 hd){
    half2v s = __builtin_bit_cast(half2v, hd);
    union { half8 h; half2v c[4]; } u, v;
    u.h = a;
    #pragma unroll
    for (int i = 0; i < 4; i++) v.c[i] = u.c[i] * s;
    return v.h;
}
// 16B global -> LDS direct (DMA; dest must be wave-uniform base + lane*16)
__device__ __forceinline__ void gl_lds16(const unsigned short* g, unsigned short* l){
    __builtin_amdgcn_global_load_lds(
        (const __attribute__((address_space(1))) void*)g,
        (__attribute__((address_space(3))) void*)l, 16, 0, 0);
}

// ---------------- ws layout (float offsets) ----------------
static const size_t o_HS = 0;          // hs-acc [Mr][768]  (raw, tanh at consumers)
static const size_t o_TS = 1167360;    // ts-acc
static const size_t o_PB = 2334720;    // bilinear acc
static const size_t Xo   = 3502080;    // time-shared region, 18,874,368 floats
// early scratch
static const size_t oEA = Xo;           // 491520
static const size_t oEE = Xo+491520;    // 1413120
static const size_t oEK = Xo+1904640;   // 235520
static const size_t oHA = Xo+2140160;   // 778240
static const size_t oHQ = Xo+2918400;   // 194560
static const size_t oSH = Xo+3112960;   // 1167360
static const size_t oST = Xo+4280320;   // 1167360
static const size_t oRS = Xo+5447680;   // 1167360
static const size_t oSEQT = Xo+6615040; // seqT f16 [B][768][512] = 786432 f
// weight^T f16 regions (float offsets; cast to ushort*)
static const size_t oWCQ = Xo;          // over dead EA, 49152 f
static const size_t oWEQ = Xo+49152;    // 49152 f
static const size_t oWHE = Xo;          // after select (EA/EE dead), 589824 f
static const size_t oWTE = Xo+589824;   // 589824 f
static const size_t oWBL = Xo;          // after ts-gmfma, all of X
// late scratch (after blmfma, over dead WblT)
static const size_t oFP = Xo;           // 1556480
static const size_t oPT = Xo+1556480;
static const size_t oQ  = Xo+2723840;
static const size_t oKT = Xo+3891200;
static const size_t oV  = Xo+5058560;
static const size_t oP2 = Xo+6225920;
static const size_t oT1 = Xo+7393280;   // ends Xo+8560640
static const size_t oWPP = Xo+8560640;  // 393216 f
static const size_t oWGQ = Xo+8953856;  // 294912 f  (WGQ|WGK|WGV contiguous -> fused qkv)
static const size_t oWGK = Xo+9248768;
static const size_t oWGV = Xo+9543680;
static const size_t oWP1 = Xo+9838592;  // 884736 f
static const size_t oWP2 = Xo+10723328; // 49152 f
// total = 22,376,448 floats = 89,505,792 B

// ---------------- front-end ----------------

__global__ __launch_bounds__(256) void k_ent_att(const float* __restrict__ att,
    const int* __restrict__ midx, const float* __restrict__ mmask, float* __restrict__ ea)
{
    int x = blockIdx.x;
    int nh = x % NHn; int e = (x / NHn) % NEn; int b = x / (NHn * NEn);
    __shared__ int   sidx[MMn];
    __shared__ float smsk[MMn];
    int t = threadIdx.x;
    if (t < MMn) { sidx[t] = midx[(b*NEn+e)*MMn + t]; smsk[t] = mmask[(b*NEn+e)*MMn + t]; }
    __syncthreads();
    float cnt = 0.f;
    for (int m = 0; m < MMn; m++) cnt += smsk[m];
    for (int c = t; c < Cn; c += 256) {
        float acc = 0.f;
        for (int m = 0; m < MMn; m++)
            acc += smsk[m] * att[((size_t)(b*NHn+nh)*Cn + sidx[m])*Cn + c];
        ea[(size_t)x*Cn + c] = acc / cnt;
    }
}

__global__ __launch_bounds__(256) void k_ent_emb(const float* __restrict__ seq,
    const int* __restrict__ midx, const float* __restrict__ mmask, float* __restrict__ ee)
{
    int x = blockIdx.x;
    int b = x / (NEn*MMn);
    int idx = midx[x]; float msk = mmask[x];
    int t = threadIdx.x;
    for (int h = t; h < Hn; h += 256)
        ee[(size_t)x*Hn + h] = msk * seq[((size_t)b*Cn + idx)*Hn + h];
}

__global__ __launch_bounds__(256) void k_htatt(const float* __restrict__ ea,
    const int* __restrict__ hts, float* __restrict__ hta)
{
    int row = blockIdx.x; int b = row / Pn;
    int he = hts[row*2], te = hts[row*2+1];
    __shared__ float sc[Cn];
    __shared__ float red[256];
    int t = threadIdx.x;
    const float* eah = ea + (size_t)(b*NEn+he)*NHn*Cn;
    const float* eat = ea + (size_t)(b*NEn+te)*NHn*Cn;
    for (int c = t; c < Cn; c += 256) {
        float a = 0.f;
        for (int nh = 0; nh < NHn; nh++) a += eah[nh*Cn+c]*eat[nh*Cn+c];
        sc[c] = a * (1.0f/NHn);
    }
    __syncthreads();
    float ps = sc[t] + sc[t+256];
    red[t] = ps; __syncthreads();
    for (int s = 128; s > 0; s >>= 1) { if (t < s) red[t] += red[t+s]; __syncthreads(); }
    float inv = 1.0f/(red[0] + 1e-5f);
    for (int c = t; c < Cn; c += 256) hta[(size_t)row*Cn + c] = sc[c]*inv;
}

__global__ __launch_bounds__(256) void k_select(const float* __restrict__ htq,
    const float* __restrict__ ekey, const float* __restrict__ ee,
    const float* __restrict__ mmask, const int* __restrict__ hts,
    float* __restrict__ selh, float* __restrict__ selt)
{
    int row = blockIdx.x; int side = blockIdx.y;
    int b = row / Pn;
    int e = hts[row*2 + side];
    __shared__ float qv[QSn];
    __shared__ float gsc[MMn];
    __shared__ float ew[MMn];
    int t = threadIdx.x;
    if (t < QSn) qv[t] = htq[(size_t)row*QSn + t];
    __syncthreads();
    if (t < MMn) {
        const float* kr = ekey + ((size_t)(b*NEn+e)*MMn + t)*QSn;
        float g = 0.f;
        for (int qq = 0; qq < QSn; qq++) g += qv[qq]*kr[qq];
        g *= SCL;
        float msk = mmask[(b*NEn+e)*MMn + t];
        gsc[t] = (msk > 0.f) ? g : NEGV;
    }
    __syncthreads();
    float mx = -1e30f;
    for (int m = 0; m < MMn; m++) mx = fmaxf(mx, gsc[m]);
    if (t < MMn) ew[t] = expf(gsc[t] - mx);
    __syncthreads();
    float s = 0.f;
    for (int m = 0; m < MMn; m++) s += ew[m];
    float invs = 1.0f/s;
    float* dst = side ? selt : selh;
    const float* eb = ee + (size_t)(b*NEn+e)*MMn*Hn;
    for (int h = t; h < Hn; h += 256) {
        float o = 0.f;
        for (int m = 0; m < MMn; m++) o += ew[m]*eb[(size_t)m*Hn + h];
        dst[(size_t)row*Hn + h] = o*invs;
    }
}

// ---------------- weight transpose/convert: W[K][N] f32 -> Wt[Npad][K] f16 ----------------
struct WD { const float* src; unsigned short* dst; int K; int N; int Npad; int t0; };
struct WT8 { WD d[8]; int nd; };

__global__ __launch_bounds__(256) void k_wtr(WT8 tab)
{
    int b = blockIdx.x;
    int i = 0;
    while (i+1 < tab.nd && b >= tab.d[i+1].t0) i++;
    WD d = tab.d[i];
    int tile = b - d.t0;
    int ktiles = d.K >> 6;
    int kt = tile % ktiles, nt = tile / ktiles;
    int k0 = kt*64, n0 = nt*64;
    __shared__ __align__(16) unsigned short tl[64][72];
    int t = threadIdx.x;
    int nl = t & 63, rq = t >> 6;
    #pragma unroll
    for (int r = 0; r < 16; r++) {
        int kl = r*4 + rq;
        float v = (n0+nl < d.N) ? d.src[(size_t)(k0+kl)*d.N + n0 + nl] : 0.f;
        tl[nl][kl] = f2h(v);
    }
    __syncthreads();
    int nn2 = t >> 2, kk0 = (t & 3) * 16;
    uint4 a = *(const uint4*)&tl[nn2][kk0];
    uint4 bq = *(const uint4*)&tl[nn2][kk0+8];
    uint4* dst = (uint4*)&d.dst[(size_t)(n0+nn2)*d.K + k0 + kk0];
    dst[0] = a; dst[1] = bq;
}

// ---------------- generic MFMA GEMM (fp16 datapath) ----------------
// out[M][N] = A[M][K](f32, up to 3 segments) @ Wt^T (Wt f16 [Npad][K])
// MODE bits: 1=atomic accumulate (k-split over z; bias pre-init), 4=+bias,
//            16=qkv routing (out=q, out2=kT transposed, out3=v; N=2304),
//            32=batched over z (aStride/wStride/oStride)
// TM: tanh applied to A-segment s when (TM>>s)&1
template<int MODE, int TM>
__global__ __launch_bounds__(256,4) void k_gmfma(
    const float* __restrict__ A0, const float* __restrict__ A1, const float* __restrict__ A2,
    int KA, int KB, int KC,
    const unsigned short* __restrict__ Wt,
    const float* __restrict__ bias, float* __restrict__ out,
    float* __restrict__ out2, float* __restrict__ out3,
    int Mtot, int N, int kchunk,
    long aStride, long wStride, long oStride)
{
    __shared__ __align__(16) unsigned short sa[64][72];
    __shared__ __align__(16) unsigned short sw[64][72];
    int t = threadIdx.x;
    int K = KA + KB + KC;
    int row0 = blockIdx.x * 64;
    int n0 = blockIdx.y * 64;
    int bz = blockIdx.z;
    const float* Ab = A0; const unsigned short* W = Wt; float* O = out;
    if (MODE & 32) { Ab += (size_t)bz*aStride; W += (size_t)bz*wStride; O += (size_t)bz*oStride; }
    int k0 = 0, k1 = K;
    if (MODE & 1) { k0 = bz*kchunk; k1 = k0 + kchunk; }
    int lane = t & 63, w = t >> 6, ln = lane & 15, q = lane >> 4;
    int sr = t >> 2;
    int sk = (t & 3) * 16;
    int rA = row0 + sr; if (rA > Mtot-1) rA = Mtot-1;

    float4v acc[4];
    #pragma unroll
    for (int mt = 0; mt < 4; mt++) acc[mt] = (float4v)0.f;

    for (int kk = k0; kk < k1; kk += 64) {
        const float* src; int kloc, Kl, seg;
        if (kk < KA)            { src = Ab; kloc = kk;          Kl = KA; seg = 0; }
        else if (kk < KA + KB)  { src = A1; kloc = kk - KA;     Kl = KB; seg = 1; }
        else                    { src = A2; kloc = kk - KA - KB; Kl = KC; seg = 2; }
        const float* ap = &src[(size_t)rA*Kl + kloc + sk];
        float4 v0 = ((const float4*)ap)[0];
        float4 v1 = ((const float4*)ap)[1];
        float4 v2 = ((const float4*)ap)[2];
        float4 v3 = ((const float4*)ap)[3];
        if (TM && ((TM >> seg) & 1)) {
            v0.x = tanhf(v0.x); v0.y = tanhf(v0.y); v0.z = tanhf(v0.z); v0.w = tanhf(v0.w);
            v1.x = tanhf(v1.x); v1.y = tanhf(v1.y); v1.z = tanhf(v1.z); v1.w = tanhf(v1.w);
            v2.x = tanhf(v2.x); v2.y = tanhf(v2.y); v2.z = tanhf(v2.z); v2.w = tanhf(v2.w);
            v3.x = tanhf(v3.x); v3.y = tanhf(v3.y); v3.z = tanhf(v3.z); v3.w = tanhf(v3.w);
        }
        const uint4* gw = (const uint4*)&W[(size_t)(n0+sr)*K + kk + sk];
        uint4 w0 = gw[0], w1 = gw[1];
        uint4 pa, pb;
        pa.x = pkrtz(v0.x, v0.y); pa.y = pkrtz(v0.z, v0.w);
        pa.z = pkrtz(v1.x, v1.y); pa.w = pkrtz(v1.z, v1.w);
        pb.x = pkrtz(v2.x, v2.y); pb.y = pkrtz(v2.z, v2.w);
        pb.z = pkrtz(v3.x, v3.y); pb.w = pkrtz(v3.z, v3.w);
        *(uint4*)&sa[sr][sk]   = pa;
        *(uint4*)&sa[sr][sk+8] = pb;
        *(uint4*)&sw[sr][sk]   = w0;
        *(uint4*)&sw[sr][sk+8] = w1;
        __syncthreads();
        half8 b0 = *(const half8*)&sw[w*16+ln][q*8];
        half8 b1 = *(const half8*)&sw[w*16+ln][32 + q*8];
        #pragma unroll
        for (int mt = 0; mt < 4; mt++) {
            half8 a0 = *(const half8*)&sa[mt*16+ln][q*8];
            half8 a1 = *(const half8*)&sa[mt*16+ln][32 + q*8];
            acc[mt] = __builtin_amdgcn_mfma_f32_16x16x32_f16(a0, b0, acc[mt], 0, 0, 0);
            acc[mt] = __builtin_amdgcn_mfma_f32_16x16x32_f16(a1, b1, acc[mt], 0, 0, 0);
        }
        __syncthreads();
    }
    // D: row(m) = (lane>>4)*4+r (A row), col(n) = lane&15 (W row)
    int nn = n0 + w*16 + ln;
    if (MODE & 16) {
        int sg = nn / Hn; int nl = nn - sg*Hn;
        #pragma unroll
        for (int mt = 0; mt < 4; mt++) {
            #pragma unroll
            for (int r = 0; r < 4; r++) {
                int row = row0 + mt*16 + q*4 + r;
                if (row >= Mtot) continue;
                float val = acc[mt][r];
                if (sg == 0)      out [(size_t)row*Hn + nl] = val;
                else if (sg == 2) out3[(size_t)row*Hn + nl] = val;
                else {
                    int bb = row / Pn, pp = row % Pn;
                    out2[((size_t)bb*Hn + nl)*Pn + pp] = val;
                }
            }
        }
        return;
    }
    if (nn >= N) return;
    float bv = (MODE & 4) ? bias[nn] : 0.f;
    #pragma unroll
    for (int mt = 0; mt < 4; mt++) {
        #pragma unroll
        for (int r = 0; r < 4; r++) {
            int row = row0 + mt*16 + q*4 + r;
            if (row >= Mtot) continue;
            float val = acc[mt][r];
            if (MODE & 1) atomicAdd(&O[(size_t)row*N + nn], val);
            else          O[(size_t)row*N + nn] = val + bv;
        }
    }
}

__global__ __launch_bounds__(256) void k_binit(const float* __restrict__ bias,
    float* __restrict__ o, int N)
{
    int idx = blockIdx.x*256 + threadIdx.x;
    o[idx] = bias[idx % N];
}

__global__ __launch_bounds__(256) void k_binit3(const float* __restrict__ b0,
    const float* __restrict__ b1, const float* __restrict__ b2, float* __restrict__ o)
{
    int idx = blockIdx.x*256 + threadIdx.x;   // < 3*Mr*Hn
    int r = idx / (Mr*Hn);
    const float* bb = (r == 0) ? b0 : ((r == 1) ? b1 : b2);
    o[idx] = bb[idx % Hn];
}

// ---------------- bilinear MFMA v9: counted-vmcnt 3-buffer DMA pipeline (T3/T4) ----------------
// Tile 64p x 64d, 128 K-chunks (one i-row each). Weights DMA'd 2 chunks ahead into a 3-buffer
// ring; per chunk: s_waitcnt vmcnt(2) + raw s_barrier (never drain to 0 in the loop).
// Hazard: stage(cc+2)->buf[(cc+2)%3] issued after barrier(cc); that buffer was last read at
// chunk cc-1 -> always >=1 barrier between cross-wave read and re-write.
__global__ __launch_bounds__(256,2) void k_blmfma(const float* __restrict__ hs,
    const float* __restrict__ ts, const unsigned short* __restrict__ Wt,
    float* __restrict__ pb)
{
    __shared__ __align__(16) unsigned short hsl[2][64][64];
    __shared__ __align__(16) unsigned short tsl[2][64][64];
    __shared__ __align__(16) unsigned short wbuf[3][64][64];
    int t = threadIdx.x;
    // bijective XCD swizzle (1728 % 8 == 0): 24 consecutive sb share one weight slice
    int bid = blockIdx.x + 24*(blockIdx.y + 12*(int)blockIdx.z);
    int sb = (bid & 7)*216 + (bid >> 3);
    int p_t = sb % 24; int r2 = sb / 24;     // r2 0..71
    int p0 = p_t * 64;                        // 24 p-tiles
    int d0 = (r2 % 12) * 64;                  // 12 d-tiles
    int g  = r2 / 12;                         // 6 -> n = 2g, 2g+1
    int lane = t & 63, w = t >> 6, ln = lane & 15, q = lane >> 4;
    int xr = (ln & 7) << 3;                   // read-side XOR (row&7 == ln&7 for all our rows)

    const unsigned short* Wd = Wt + (size_t)d0*49152;
    // stage chunk cc (64 d-rows x 64 k) into wbuf[bufi]: linear dest, pre-swizzled source
    auto stage = [&](int cc, int bufi){
        int n2 = 2*g + (cc >> 6);
        size_t kb = (size_t)n2*4096 + (size_t)(cc & 63)*64;
        #pragma unroll
        for (int pass = 0; pass < 2; pass++) {
            int r = pass*32 + (t >> 3);
            int c0s = (t & 7) * 8;
            gl_lds16(Wd + (size_t)r*49152 + kb + (c0s ^ ((r & 7) << 3)),
                     &wbuf[bufi][r][c0s]);
        }
    };
    stage(0, 0);   // weight DMA overlaps the tanh-heavy hs/ts staging below
    stage(1, 1);

    {   // stage hs/ts for BOTH n halves (tanh fused, f32->f16, XOR-swizzled cols)
        int p = t & 63; int s = t >> 6;       // s 0..3
        int nn = s >> 1; int c0 = (s & 1) * 32;
        int xw = (p & 7) << 3;
        int pr = p0 + p; if (pr > Mr-1) pr = Mr-1;
        int n = 2*g + nn;
        const float* hp = hs + (size_t)pr*Hn + n*64 + c0;
        const float* tp = ts + (size_t)pr*Hn + n*64 + c0;
        #pragma unroll
        for (int b2 = 0; b2 < 2; b2++) {
            const float4* hp4 = (const float4*)(hp + b2*16);
            const float4* tp4 = (const float4*)(tp + b2*16);
            float4 x0=hp4[0], x1=hp4[1], x2=hp4[2], x3=hp4[3];
            uint4 oh, oh2;
            oh.x = pkrtz(tanhf(x0.x),tanhf(x0.y)); oh.y = pkrtz(tanhf(x0.z),tanhf(x0.w));
            oh.z = pkrtz(tanhf(x1.x),tanhf(x1.y)); oh.w = pkrtz(tanhf(x1.z),tanhf(x1.w));
            oh2.x = pkrtz(tanhf(x2.x),tanhf(x2.y)); oh2.y = pkrtz(tanhf(x2.z),tanhf(x2.w));
            oh2.z = pkrtz(tanhf(x3.x),tanhf(x3.y)); oh2.w = pkrtz(tanhf(x3.z),tanhf(x3.w));
            *(uint4*)&hsl[nn][p][(c0 + b2*16)     ^ xw] = oh;
            *(uint4*)&hsl[nn][p][(c0 + b2*16 + 8) ^ xw] = oh2;
            float4 y0=tp4[0], y1=tp4[1], y2=tp4[2], y3=tp4[3];
            uint4 ot, ot2;
            ot.x = pkrtz(tanhf(y0.x),tanhf(y0.y)); ot.y = pkrtz(tanhf(y0.z),tanhf(y0.w));
            ot.z = pkrtz(tanhf(y1.x),tanhf(y1.y)); ot.w = pkrtz(tanhf(y1.z),tanhf(y1.w));
            ot2.x = pkrtz(tanhf(y2.x),tanhf(y2.y)); ot2.y = pkrtz(tanhf(y2.z),tanhf(y2.w));
            ot2.z = pkrtz(tanhf(y3.x),tanhf(y3.y)); ot2.w = pkrtz(tanhf(y3.z),tanhf(y3.w));
            *(uint4*)&tsl[nn][p][(c0 + b2*16)     ^ xw] = ot;
            *(uint4*)&tsl[nn][p][(c0 + b2*16 + 8) ^ xw] = ot2;
        }
    }
    __syncthreads();   // drains stage(0),stage(1) DMA + hs/ts ds_writes (full drain, once)

    float4v acc[4];
    #pragma unroll
    for (int e = 0; e < 4; e++) acc[e] = (float4v)0.f;

    #pragma unroll
    for (int nn = 0; nn < 2; nn++) {
        // ts fragments for this n, held in regs across the 64 chunks
        half8 tsr0[4], tsr1[4];
        #pragma unroll
        for (int e = 0; e < 4; e++) {
            tsr0[e] = *(const half8*)&tsl[nn][e*16+ln][(q*8) ^ xr];
            tsr1[e] = *(const half8*)&tsl[nn][e*16+ln][(32 + q*8) ^ xr];
        }
        for (int ci = 0; ci < 64; ci++) {
            int cc = nn*64 + ci;
            if (cc) {
                // counted wait: forces stage(cc) complete, leaves stage(cc+1) in flight
                asm volatile("s_waitcnt vmcnt(2)" ::: "memory");
                __builtin_amdgcn_s_barrier();
            }
            if (cc + 2 < 128) stage(cc + 2, (cc + 2) % 3);
            int buf = cc % 3;
            uint32 hd[4];
            #pragma unroll
            for (int e = 0; e < 4; e++) {
                uint32 hv = hsl[nn][e*16+ln][ci ^ xr];
                hd[e] = __builtin_amdgcn_perm(hv, hv, 0x01000100u);
            }
            #pragma unroll
            for (int c = 0; c < 2; c++) {
                half8 wf = *(const half8*)&wbuf[buf][w*16+ln][(c*32 + q*8) ^ xr];
                #pragma unroll
                for (int e = 0; e < 4; e++) {
                    half8 bfr = mulsplat(c ? tsr1[e] : tsr0[e], hd[e]);
                    acc[e] = __builtin_amdgcn_mfma_f32_16x16x32_f16(wf, bfr, acc[e], 0, 0, 0);
                }
            }
        }
    }
    #pragma unroll
    for (int e = 0; e < 4; e++) {
        int p = p0 + e*16 + ln;
        if (p >= Mr) continue;
        int dbase = d0 + w*16 + q*4;
        #pragma unroll
        for (int r = 0; r < 4; r++)
            atomicAdd(&pb[(size_t)p*Hn + dbase + r], acc[e][r]);
    }
}

// ---------------- back-end ----------------

__global__ __launch_bounds__(256) void k_featpp(const float* __restrict__ pairbl,
    const float* __restrict__ pos, const int* __restrict__ hts, float* __restrict__ fpp)
{
    int row = blockIdx.x; int t = threadIdx.x;
    int he = hts[row*2], te = hts[row*2+1];
    float* dst = fpp + (size_t)row*1024;
    if (t < 128) { dst[t] = pos[he*128 + t]; dst[896 + t] = pos[te*128 + t]; }
    for (int h = t; h < Hn; h += 256) dst[128 + h] = pairbl[(size_t)row*Hn + h];
}

// pair2 = tanh(pairT) + softmax(q@kT masked) @ v   (V read once; 3 d-chunks in regs)
__global__ __launch_bounds__(256) void k_graph(const float* __restrict__ q,
    const float* __restrict__ kT, const float* __restrict__ v, const float* __restrict__ vis,
    const float* __restrict__ pairT, float* __restrict__ pair2)
{
    int row = blockIdx.x; int b = row / Pn; int p = row % Pn;
    __shared__ float qs[Hn];
    __shared__ float sc[Pn];
    __shared__ float red[256];
    int t = threadIdx.x;
    for (int h = t; h < Hn; h += 256) qs[h] = q[(size_t)row*Hn + h];
    __syncthreads();
    for (int qq = t; qq < Pn; qq += 256) {
        const float* kcol = kT + (size_t)b*Hn*Pn + qq;
        float a = 0.f;
        for (int h = 0; h < Hn; h++) a += qs[h]*kcol[(size_t)h*Pn];
        a *= SCL;
        float ms = vis[((size_t)b*Pn + p)*Pn + qq];
        sc[qq] = (ms > 0.f) ? a : NEGV;
    }
    __syncthreads();
    float mx = -1e30f;
    for (int qq = t; qq < Pn; qq += 256) mx = fmaxf(mx, sc[qq]);
    red[t] = mx; __syncthreads();
    for (int s = 128; s > 0; s >>= 1) { if (t < s) red[t] = fmaxf(red[t], red[t+s]); __syncthreads(); }
    mx = red[0];
    __syncthreads();
    float ps = 0.f;
    for (int qq = t; qq < Pn; qq += 256) { float e2 = expf(sc[qq]-mx); sc[qq] = e2; ps += e2; }
    red[t] = ps; __syncthreads();
    for (int s = 128; s > 0; s >>= 1) { if (t < s) red[t] += red[t+s]; __syncthreads(); }
    float invs = 1.0f/red[0];
    __syncthreads();
    float a0 = 0.f, a1 = 0.f, a2 = 0.f;
    for (int qq = 0; qq < Pn; qq++) {
        float sv = sc[qq];
        const float* vr = v + ((size_t)b*Pn+qq)*Hn + t;
        a0 += sv*vr[0]; a1 += sv*vr[256]; a2 += sv*vr[512];
    }
    const float* pt = pairT + (size_t)row*Hn + t;
    float* o = pair2 + (size_t)row*Hn + t;
    o[0]   = tanhf(pt[0])   + a0*invs;
    o[256] = tanhf(pt[256]) + a1*invs;
    o[512] = tanhf(pt[512]) + a2*invs;
}

__global__ __launch_bounds__(256) void k_fillu(unsigned int* p, unsigned int v, int n){
    int i = blockIdx.x*256 + threadIdx.x;
    if (i < n) p[i] = v;
}

// ---------------- launch ----------------
extern "C" void kernel_launch(void* const* d_in, const int* in_sizes, int n_in,
                              void* d_out, int out_size, void* d_ws, size_t ws_size,
                              hipStream_t stream)
{
    const float* seq  = (const float*)d_in[0];
    const float* att  = (const float*)d_in[1];
    const int*   midx = (const int*)d_in[2];
    const float* mmask= (const float*)d_in[3];
    const int*   hts  = (const int*)d_in[4];
    const float* vis  = (const float*)d_in[5];
    const float* Wcq = (const float*)d_in[6];  const float* bcq = (const float*)d_in[7];
    const float* Weq = (const float*)d_in[8];  const float* beq = (const float*)d_in[9];
    const float* Whe = (const float*)d_in[10]; const float* bhe = (const float*)d_in[11];
    const float* Wte = (const float*)d_in[12]; const float* bte = (const float*)d_in[13];
    const float* Wbl = (const float*)d_in[14]; const float* bbl = (const float*)d_in[15];
    const float* Wpp = (const float*)d_in[16]; const float* bpp = (const float*)d_in[17];
    const float* Wgq = (const float*)d_in[18];
    const float* Wgk = (const float*)d_in[19];
    const float* Wgv = (const float*)d_in[20];
    const float* Wp1 = (const float*)d_in[21]; const float* bp1 = (const float*)d_in[22];
    const float* Wp2 = (const float*)d_in[23]; const float* bp2 = (const float*)d_in[24];
    const float* pos = (const float*)d_in[25];
    float* ws = (float*)d_ws;
    float* out = (float*)d_out;
    const float* nul = nullptr;
    float* nulw = nullptr;

    if (ws_size < 89505792ULL) {
        int n = out_size/2;
        k_fillu<<<(n+255)/256, 256, 0, stream>>>((unsigned int*)d_out, 0x476A476Au, n);
        return;
    }

    unsigned short* WCQt = (unsigned short*)(ws + oWCQ);
    unsigned short* WEQt = (unsigned short*)(ws + oWEQ);
    unsigned short* SEQt = (unsigned short*)(ws + oSEQT);
    unsigned short* WHEt = (unsigned short*)(ws + oWHE);
    unsigned short* WTEt = (unsigned short*)(ws + oWTE);
    unsigned short* WBLt = (unsigned short*)(ws + oWBL);
    unsigned short* WPPt = (unsigned short*)(ws + oWPP);
    unsigned short* WGQt = (unsigned short*)(ws + oWGQ);
    unsigned short* WP1t = (unsigned short*)(ws + oWP1);
    unsigned short* WP2t = (unsigned short*)(ws + oWP2);

    // ---- front-end ----
    k_ent_att<<<Bn*NEn*NHn, 256, 0, stream>>>(att, midx, mmask, ws + oEA);
    k_ent_emb<<<Bn*NEn*MMn, 256, 0, stream>>>(seq, midx, mmask, ws + oEE);
    k_htatt<<<Mr, 256, 0, stream>>>(ws + oEA, hts, ws + oHA);

    // Wcq/Weq + per-batch seq transposes (EA dead)
    {
        WT8 tb{}; tb.nd = 6;
        tb.d[0] = { Wcq, WCQt, 768, 128, 128, 0 };
        tb.d[1] = { Weq, WEQt, 768, 128, 128, 24 };
        for (int b = 0; b < 4; b++)
            tb.d[2+b] = { seq + (size_t)b*Cn*Hn, SEQt + (size_t)b*Hn*Cn, Cn, Hn, Hn, 48 + b*96 };
        k_wtr<<<432, 256, 0, stream>>>(tb);
    }
    // rs = ht_att @ seq[b]   (batched MFMA)
    k_gmfma<32,0><<<dim3(6,12,4), 256, 0, stream>>>(ws + oHA, nul, nul, Cn, 0, 0,
        SEQt, nul, ws + oRS, nulw, nulw, Pn, Hn, 0,
        (long)Pn*Cn, (long)Hn*Cn, (long)Pn*Hn);
    // htq = rs @ Wcq + bcq
    k_gmfma<4,0><<<dim3(24,2,1), 256, 0, stream>>>(ws + oRS, nul, nul, Hn, 0, 0,
        WCQt, bcq, ws + oHQ, nulw, nulw, Mr, QSn, 0, 0, 0, 0);
    // ent_key = ent_emb @ Weq + beq
    k_gmfma<4,0><<<dim3(29,2,1), 256, 0, stream>>>(ws + oEE, nul, nul, Hn, 0, 0,
        WEQt, beq, ws + oEK, nulw, nulw, Bn*NEn*MMn, QSn, 0, 0, 0, 0);
    k_select<<<dim3(Mr,2), 256, 0, stream>>>(ws + oHQ, ws + oEK, ws + oEE,
        mmask, hts, ws + oSH, ws + oST);

    // Whe/Wte transposes (EA/EE/EK/HQ dead)
    {
        WT8 tb{}; tb.nd = 2;
        tb.d[0] = { Whe, WHEt, 1536, 768, 768, 0 };
        tb.d[1] = { Wte, WTEt, 1536, 768, 768, 288 };
        k_wtr<<<576, 256, 0, stream>>>(tb);
    }
    // bias-init hs/ts/pb in one pass (contiguous), then atomic k-split GEMMs (raw, tanh at consumers)
    k_binit3<<<(3*Mr*Hn)/256, 256, 0, stream>>>(bhe, bte, bbl, ws + o_HS);
    k_gmfma<1,0><<<dim3(24,12,3), 256, 0, stream>>>(ws + oSH, ws + oRS, nul, Hn, Hn, 0,
        WHEt, nul, ws + o_HS, nulw, nulw, Mr, Hn, 512, 0, 0, 0);
    k_gmfma<1,0><<<dim3(24,12,3), 256, 0, stream>>>(ws + oST, ws + oRS, nul, Hn, Hn, 0,
        WTEt, nul, ws + o_TS, nulw, nulw, Mr, Hn, 512, 0, 0, 0);

    // bilinear: Wbl transpose (all X dead), MFMA v9 (counted-vmcnt 3-buffer pipeline)
    {
        WT8 tb{}; tb.nd = 1;
        tb.d[0] = { Wbl, WBLt, 49152, 768, 768, 0 };
        k_wtr<<<9216, 256, 0, stream>>>(tb);
    }
    k_blmfma<<<dim3(24,12,6), 256, 0, stream>>>(ws + o_HS, ws + o_TS, WBLt, ws + o_PB);

    k_featpp<<<Mr, 256, 0, stream>>>(ws + o_PB, pos, hts, ws + oFP);

    // late weight transposes (WblT dead)
    {
        WT8 tb{}; tb.nd = 6;
        tb.d[0] = { Wpp, WPPt, 1024, 768, 768, 0 };
        tb.d[1] = { Wgq, WGQt, 768, 768, 768, 192 };
        tb.d[2] = { Wgk, (unsigned short*)(ws + oWGK), 768, 768, 768, 336 };
        tb.d[3] = { Wgv, (unsigned short*)(ws + oWGV), 768, 768, 768, 480 };
        tb.d[4] = { Wp1, WP1t, 2304, 768, 768, 624 };
        tb.d[5] = { Wp2, WP2t, 768, 97, 128, 1056 };
        k_wtr<<<1080, 256, 0, stream>>>(tb);
    }
    // pairT-acc = fpp @ Wpp + bpp  (raw; tanh at consumers)
    k_binit<<<(Mr*Hn)/256, 256, 0, stream>>>(bpp, ws + oPT, Hn);
    k_gmfma<1,0><<<dim3(24,12,2), 256, 0, stream>>>(ws + oFP, nul, nul, 1024, 0, 0,
        WPPt, nul, ws + oPT, nulw, nulw, Mr, Hn, 512, 0, 0, 0);
    // fused q|kT|v = tanh(pairT) @ [Wgq|Wgk|Wgv]  (weights contiguous, N=2304)
    k_gmfma<16,1><<<dim3(24,36,1), 256, 0, stream>>>(ws + oPT, nul, nul, Hn, 0, 0,
        WGQt, nul, ws + oQ, ws + oKT, ws + oV, Mr, 3*Hn, 0, 0, 0, 0);
    k_graph<<<Mr, 256, 0, stream>>>(ws + oQ, ws + oKT, ws + oV, vis, ws + oPT, ws + oP2);
    // t1-acc = [tanh(hs)|tanh(ts)|pair2] @ Wp1 + bp1  (raw; tanh at final gemm)
    k_binit<<<(Mr*Hn)/256, 256, 0, stream>>>(bp1, ws + oT1, Hn);
    k_gmfma<1,3><<<dim3(24,12,3), 256, 0, stream>>>(ws + o_HS, ws + o_TS, ws + oP2,
        Hn, Hn, Hn, WP1t, nul, ws + oT1, nulw, nulw, Mr, Hn, 768, 0, 0, 0);
    // logits = tanh(t1) @ Wp2 + bp2
    k_gmfma<4,1><<<dim3(24,2,1), 256, 0, stream>>>(ws + oT1, nul, nul, Hn, 0, 0,
        WP2t, bp2, out, nulw, nulw, Mr, 97, 0, 0, 0, 0);
}

// Round 9
// 1037.689 us; speedup vs baseline: 1.0201x; 1.0201x over previous
//
#include <hip/hip_runtime.h>
#include <hip/hip_bf16.h>

#define Bn   4
#define Cn   512
#define Hn   768
#define NHn  12
#define NEn  20
#define MMn  23
#define Pn   380
#define Mr   1520     // B*P
#define QSn  128
#define NEGV (-10000.0f)
#define SCL  0.036084391824351615f   // 1/sqrt(768)

typedef unsigned int uint32;
typedef __attribute__((ext_vector_type(4))) float float4v;
typedef __attribute__((ext_vector_type(2))) _Float16 half2v;
typedef __attribute__((ext_vector_type(2))) __fp16 fp16x2;
typedef __attribute__((ext_vector_type(8))) _Float16 half8;

// f32 -> f16 single element (RNE, v_cvt_f16_f32)
__device__ __forceinline__ unsigned short f2h(float f){
    return __builtin_bit_cast(unsigned short, (_Float16)f);
}
// pack 2 f32 -> 2 f16 in one v_cvt_pkrtz_f16_f32
__device__ __forceinline__ uint32 pkrtz(float a, float b){
    fp16x2 h = __builtin_amdgcn_cvt_pkrtz(a, b);
    return __builtin_bit_cast(uint32, h);
}
// half8 * splat(half2) elementwise -> 4x v_pk_mul_f16
__device__ __forceinline__ half8 mulsplat(half8 a, uint32 hd){
    half2v s = __builtin_bit_cast(half2v, hd);
    union { half8 h; half2v c[4]; } u, v;
    u.h = a;
    #pragma unroll
    for (int i = 0; i < 4; i++) v.c[i] = u.c[i] * s;
    return v.h;
}
// 16B global -> LDS direct (DMA; dest must be wave-uniform base + lane*16)
__device__ __forceinline__ void gl_lds16(const unsigned short* g, unsigned short* l){
    __builtin_amdgcn_global_load_lds(
        (const __attribute__((address_space(1))) void*)g,
        (__attribute__((address_space(3))) void*)l, 16, 0, 0);
}

// ---------------- ws layout (float offsets) ----------------
static const size_t o_HS = 0;          // hs-acc [Mr][768]  (raw, tanh at consumers)
static const size_t o_TS = 1167360;    // ts-acc
static const size_t o_PB = 2334720;    // bilinear acc
static const size_t Xo   = 3502080;    // time-shared region, 18,874,368 floats
// early scratch
static const size_t oEA = Xo;           // 491520
static const size_t oEE = Xo+491520;    // 1413120
static const size_t oEK = Xo+1904640;   // 235520
static const size_t oHA = Xo+2140160;   // 778240
static const size_t oHQ = Xo+2918400;   // 194560
static const size_t oSH = Xo+3112960;   // 1167360
static const size_t oST = Xo+4280320;   // 1167360
static const size_t oRS = Xo+5447680;   // 1167360
static const size_t oSEQT = Xo+6615040; // seqT f16 [B][768][512] = 786432 f
// weight^T f16 regions (float offsets; cast to ushort*)
static const size_t oWCQ = Xo;          // over dead EA, 49152 f
static const size_t oWEQ = Xo+49152;    // 49152 f
static const size_t oWHE = Xo;          // after select (EA/EE dead), 589824 f
static const size_t oWTE = Xo+589824;   // 589824 f
static const size_t oWBL = Xo;          // after ts-gmfma, all of X
// late scratch (after blmfma, over dead WblT)
static const size_t oFP = Xo;           // 1556480
static const size_t oPT = Xo+1556480;
static const size_t oQ  = Xo+2723840;
static const size_t oKT = Xo+3891200;
static const size_t oV  = Xo+5058560;
static const size_t oP2 = Xo+6225920;
static const size_t oT1 = Xo+7393280;   // ends Xo+8560640
static const size_t oWPP = Xo+8560640;  // 393216 f
static const size_t oWGQ = Xo+8953856;  // 294912 f  (WGQ|WGK|WGV contiguous -> fused qkv)
static const size_t oWGK = Xo+9248768;
static const size_t oWGV = Xo+9543680;
static const size_t oWP1 = Xo+9838592;  // 884736 f
static const size_t oWP2 = Xo+10723328; // 49152 f
// total = 22,376,448 floats = 89,505,792 B

// ---------------- front-end ----------------

__global__ __launch_bounds__(256) void k_ent_att(const float* __restrict__ att,
    const int* __restrict__ midx, const float* __restrict__ mmask, float* __restrict__ ea)
{
    int x = blockIdx.x;
    int nh = x % NHn; int e = (x / NHn) % NEn; int b = x / (NHn * NEn);
    __shared__ int   sidx[MMn];
    __shared__ float smsk[MMn];
    int t = threadIdx.x;
    if (t < MMn) { sidx[t] = midx[(b*NEn+e)*MMn + t]; smsk[t] = mmask[(b*NEn+e)*MMn + t]; }
    __syncthreads();
    float cnt = 0.f;
    for (int m = 0; m < MMn; m++) cnt += smsk[m];
    for (int c = t; c < Cn; c += 256) {
        float acc = 0.f;
        for (int m = 0; m < MMn; m++)
            acc += smsk[m] * att[((size_t)(b*NHn+nh)*Cn + sidx[m])*Cn + c];
        ea[(size_t)x*Cn + c] = acc / cnt;
    }
}

__global__ __launch_bounds__(256) void k_ent_emb(const float* __restrict__ seq,
    const int* __restrict__ midx, const float* __restrict__ mmask, float* __restrict__ ee)
{
    int x = blockIdx.x;
    int b = x / (NEn*MMn);
    int idx = midx[x]; float msk = mmask[x];
    int t = threadIdx.x;
    for (int h = t; h < Hn; h += 256)
        ee[(size_t)x*Hn + h] = msk * seq[((size_t)b*Cn + idx)*Hn + h];
}

__global__ __launch_bounds__(256) void k_htatt(const float* __restrict__ ea,
    const int* __restrict__ hts, float* __restrict__ hta)
{
    int row = blockIdx.x; int b = row / Pn;
    int he = hts[row*2], te = hts[row*2+1];
    __shared__ float sc[Cn];
    __shared__ float red[256];
    int t = threadIdx.x;
    const float* eah = ea + (size_t)(b*NEn+he)*NHn*Cn;
    const float* eat = ea + (size_t)(b*NEn+te)*NHn*Cn;
    for (int c = t; c < Cn; c += 256) {
        float a = 0.f;
        for (int nh = 0; nh < NHn; nh++) a += eah[nh*Cn+c]*eat[nh*Cn+c];
        sc[c] = a * (1.0f/NHn);
    }
    __syncthreads();
    float ps = sc[t] + sc[t+256];
    red[t] = ps; __syncthreads();
    for (int s = 128; s > 0; s >>= 1) { if (t < s) red[t] += red[t+s]; __syncthreads(); }
    float inv = 1.0f/(red[0] + 1e-5f);
    for (int c = t; c < Cn; c += 256) hta[(size_t)row*Cn + c] = sc[c]*inv;
}

__global__ __launch_bounds__(256) void k_select(const float* __restrict__ htq,
    const float* __restrict__ ekey, const float* __restrict__ ee,
    const float* __restrict__ mmask, const int* __restrict__ hts,
    float* __restrict__ selh, float* __restrict__ selt)
{
    int row = blockIdx.x; int side = blockIdx.y;
    int b = row / Pn;
    int e = hts[row*2 + side];
    __shared__ float qv[QSn];
    __shared__ float gsc[MMn];
    __shared__ float ew[MMn];
    int t = threadIdx.x;
    if (t < QSn) qv[t] = htq[(size_t)row*QSn + t];
    __syncthreads();
    if (t < MMn) {
        const float* kr = ekey + ((size_t)(b*NEn+e)*MMn + t)*QSn;
        float g = 0.f;
        for (int qq = 0; qq < QSn; qq++) g += qv[qq]*kr[qq];
        g *= SCL;
        float msk = mmask[(b*NEn+e)*MMn + t];
        gsc[t] = (msk > 0.f) ? g : NEGV;
    }
    __syncthreads();
    float mx = -1e30f;
    for (int m = 0; m < MMn; m++) mx = fmaxf(mx, gsc[m]);
    if (t < MMn) ew[t] = expf(gsc[t] - mx);
    __syncthreads();
    float s = 0.f;
    for (int m = 0; m < MMn; m++) s += ew[m];
    float invs = 1.0f/s;
    float* dst = side ? selt : selh;
    const float* eb = ee + (size_t)(b*NEn+e)*MMn*Hn;
    for (int h = t; h < Hn; h += 256) {
        float o = 0.f;
        for (int m = 0; m < MMn; m++) o += ew[m]*eb[(size_t)m*Hn + h];
        dst[(size_t)row*Hn + h] = o*invs;
    }
}

// ---------------- weight transpose/convert: W[K][N] f32 -> Wt[Npad][K] f16 ----------------
struct WD { const float* src; unsigned short* dst; int K; int N; int Npad; int t0; };
struct WT8 { WD d[8]; int nd; };

__global__ __launch_bounds__(256) void k_wtr(WT8 tab)
{
    int b = blockIdx.x;
    int i = 0;
    while (i+1 < tab.nd && b >= tab.d[i+1].t0) i++;
    WD d = tab.d[i];
    int tile = b - d.t0;
    int ktiles = d.K >> 6;
    int kt = tile % ktiles, nt = tile / ktiles;
    int k0 = kt*64, n0 = nt*64;
    __shared__ __align__(16) unsigned short tl[64][72];
    int t = threadIdx.x;
    int nl = t & 63, rq = t >> 6;
    #pragma unroll
    for (int r = 0; r < 16; r++) {
        int kl = r*4 + rq;
        float v = (n0+nl < d.N) ? d.src[(size_t)(k0+kl)*d.N + n0 + nl] : 0.f;
        tl[nl][kl] = f2h(v);
    }
    __syncthreads();
    int nn2 = t >> 2, kk0 = (t & 3) * 16;
    uint4 a = *(const uint4*)&tl[nn2][kk0];
    uint4 bq = *(const uint4*)&tl[nn2][kk0+8];
    uint4* dst = (uint4*)&d.dst[(size_t)(n0+nn2)*d.K + k0 + kk0];
    dst[0] = a; dst[1] = bq;
}

// ---------------- generic MFMA GEMM (fp16 datapath) ----------------
// out[M][N] = A[M][K](f32, up to 3 segments) @ Wt^T (Wt f16 [Npad][K])
// MODE bits: 1=atomic accumulate (k-split over z; bias pre-init), 4=+bias,
//            16=qkv routing (out=q, out2=kT transposed, out3=v; N=2304),
//            32=batched over z (aStride/wStride/oStride)
// TM: tanh applied to A-segment s when (TM>>s)&1
template<int MODE, int TM>
__global__ __launch_bounds__(256,4) void k_gmfma(
    const float* __restrict__ A0, const float* __restrict__ A1, const float* __restrict__ A2,
    int KA, int KB, int KC,
    const unsigned short* __restrict__ Wt,
    const float* __restrict__ bias, float* __restrict__ out,
    float* __restrict__ out2, float* __restrict__ out3,
    int Mtot, int N, int kchunk,
    long aStride, long wStride, long oStride)
{
    __shared__ __align__(16) unsigned short sa[64][72];
    __shared__ __align__(16) unsigned short sw[64][72];
    int t = threadIdx.x;
    int K = KA + KB + KC;
    int row0 = blockIdx.x * 64;
    int n0 = blockIdx.y * 64;
    int bz = blockIdx.z;
    const float* Ab = A0; const unsigned short* W = Wt; float* O = out;
    if (MODE & 32) { Ab += (size_t)bz*aStride; W += (size_t)bz*wStride; O += (size_t)bz*oStride; }
    int k0 = 0, k1 = K;
    if (MODE & 1) { k0 = bz*kchunk; k1 = k0 + kchunk; }
    int lane = t & 63, w = t >> 6, ln = lane & 15, q = lane >> 4;
    int sr = t >> 2;
    int sk = (t & 3) * 16;
    int rA = row0 + sr; if (rA > Mtot-1) rA = Mtot-1;

    float4v acc[4];
    #pragma unroll
    for (int mt = 0; mt < 4; mt++) acc[mt] = (float4v)0.f;

    for (int kk = k0; kk < k1; kk += 64) {
        const float* src; int kloc, Kl, seg;
        if (kk < KA)            { src = Ab; kloc = kk;          Kl = KA; seg = 0; }
        else if (kk < KA + KB)  { src = A1; kloc = kk - KA;     Kl = KB; seg = 1; }
        else                    { src = A2; kloc = kk - KA - KB; Kl = KC; seg = 2; }
        const float* ap = &src[(size_t)rA*Kl + kloc + sk];
        float4 v0 = ((const float4*)ap)[0];
        float4 v1 = ((const float4*)ap)[1];
        float4 v2 = ((const float4*)ap)[2];
        float4 v3 = ((const float4*)ap)[3];
        if (TM && ((TM >> seg) & 1)) {
            v0.x = tanhf(v0.x); v0.y = tanhf(v0.y); v0.z = tanhf(v0.z); v0.w = tanhf(v0.w);
            v1.x = tanhf(v1.x); v1.y = tanhf(v1.y); v1.z = tanhf(v1.z); v1.w = tanhf(v1.w);
            v2.x = tanhf(v2.x); v2.y = tanhf(v2.y); v2.z = tanhf(v2.z); v2.w = tanhf(v2.w);
            v3.x = tanhf(v3.x); v3.y = tanhf(v3.y); v3.z = tanhf(v3.z); v3.w = tanhf(v3.w);
        }
        const uint4* gw = (const uint4*)&W[(size_t)(n0+sr)*K + kk + sk];
        uint4 w0 = gw[0], w1 = gw[1];
        uint4 pa, pb;
        pa.x = pkrtz(v0.x, v0.y); pa.y = pkrtz(v0.z, v0.w);
        pa.z = pkrtz(v1.x, v1.y); pa.w = pkrtz(v1.z, v1.w);
        pb.x = pkrtz(v2.x, v2.y); pb.y = pkrtz(v2.z, v2.w);
        pb.z = pkrtz(v3.x, v3.y); pb.w = pkrtz(v3.z, v3.w);
        *(uint4*)&sa[sr][sk]   = pa;
        *(uint4*)&sa[sr][sk+8] = pb;
        *(uint4*)&sw[sr][sk]   = w0;
        *(uint4*)&sw[sr][sk+8] = w1;
        __syncthreads();
        half8 b0 = *(const half8*)&sw[w*16+ln][q*8];
        half8 b1 = *(const half8*)&sw[w*16+ln][32 + q*8];
        #pragma unroll
        for (int mt = 0; mt < 4; mt++) {
            half8 a0 = *(const half8*)&sa[mt*16+ln][q*8];
            half8 a1 = *(const half8*)&sa[mt*16+ln][32 + q*8];
            acc[mt] = __builtin_amdgcn_mfma_f32_16x16x32_f16(a0, b0, acc[mt], 0, 0, 0);
            acc[mt] = __builtin_amdgcn_mfma_f32_16x16x32_f16(a1, b1, acc[mt], 0, 0, 0);
        }
        __syncthreads();
    }
    // D: row(m) = (lane>>4)*4+r (A row), col(n) = lane&15 (W row)
    int nn = n0 + w*16 + ln;
    if (MODE & 16) {
        int sg = nn / Hn; int nl = nn - sg*Hn;
        #pragma unroll
        for (int mt = 0; mt < 4; mt++) {
            #pragma unroll
            for (int r = 0; r < 4; r++) {
                int row = row0 + mt*16 + q*4 + r;
                if (row >= Mtot) continue;
                float val = acc[mt][r];
                if (sg == 0)      out [(size_t)row*Hn + nl] = val;
                else if (sg == 2) out3[(size_t)row*Hn + nl] = val;
                else {
                    int bb = row / Pn, pp = row % Pn;
                    out2[((size_t)bb*Hn + nl)*Pn + pp] = val;
                }
            }
        }
        return;
    }
    if (nn >= N) return;
    float bv = (MODE & 4) ? bias[nn] : 0.f;
    #pragma unroll
    for (int mt = 0; mt < 4; mt++) {
        #pragma unroll
        for (int r = 0; r < 4; r++) {
            int row = row0 + mt*16 + q*4 + r;
            if (row >= Mtot) continue;
            float val = acc[mt][r];
            if (MODE & 1) atomicAdd(&O[(size_t)row*N + nn], val);
            else          O[(size_t)row*N + nn] = val + bv;
        }
    }
}

__global__ __launch_bounds__(256) void k_binit(const float* __restrict__ bias,
    float* __restrict__ o, int N)
{
    int idx = blockIdx.x*256 + threadIdx.x;
    o[idx] = bias[idx % N];
}

__global__ __launch_bounds__(256) void k_binit3(const float* __restrict__ b0,
    const float* __restrict__ b1, const float* __restrict__ b2, float* __restrict__ o)
{
    int idx = blockIdx.x*256 + threadIdx.x;   // < 3*Mr*Hn
    int r = idx / (Mr*Hn);
    const float* bb = (r == 0) ? b0 : ((r == 1) ? b1 : b2);
    o[idx] = bb[idx % Hn];
}

// ---------------- bilinear MFMA v10: 128-p tile, global_load_lds staging (v8 structure) ----------------
// Tile 128p x 64d, 128 K-chunks (one i-row each). Weight slice shared by 12 p-blocks (was 24)
// -> weight L2 traffic halved; 16 MFMA/wave between barriers (was 8) -> drain cost per FLOP halved.
// Same verified swizzle algebra as v8 (e extended 4->8). Plain dbuf + one barrier per chunk.
__global__ __launch_bounds__(256,2) void k_blmfma(const float* __restrict__ hs,
    const float* __restrict__ ts, const unsigned short* __restrict__ Wt,
    float* __restrict__ pb)
{
    __shared__ __align__(16) unsigned short hsl[2][128][64];
    __shared__ __align__(16) unsigned short tsl[2][128][64];
    __shared__ __align__(16) unsigned short wbuf[2][64][64];
    int t = threadIdx.x;
    // bijective XCD swizzle (864 % 8 == 0): 12 consecutive sb share one weight slice
    int bid = blockIdx.x + 12*(blockIdx.y + 12*(int)blockIdx.z);
    int sb = (bid & 7)*108 + (bid >> 3);
    int p_t = sb % 12; int r2 = sb / 12;     // r2 0..71
    int p0 = p_t * 128;                       // 12 p-tiles
    int d0 = (r2 % 12) * 64;                  // 12 d-tiles
    int g  = r2 / 12;                         // 6 -> n = 2g, 2g+1
    int lane = t & 63, w = t >> 6, ln = lane & 15, q = lane >> 4;
    int xr = (ln & 7) << 3;                   // read-side XOR (row&7 == ln&7 for all our rows)

    const unsigned short* Wd = Wt + (size_t)d0*49152;
    // stage chunk cc (64 d-rows x 64 k) into wbuf[bufi]: linear dest, pre-swizzled source
    auto stage = [&](int cc, int bufi){
        int n2 = 2*g + (cc >> 6);
        size_t kb = (size_t)n2*4096 + (size_t)(cc & 63)*64;
        #pragma unroll
        for (int pass = 0; pass < 2; pass++) {
            int r = pass*32 + (t >> 3);
            int c0s = (t & 7) * 8;
            gl_lds16(Wd + (size_t)r*49152 + kb + (c0s ^ ((r & 7) << 3)),
                     &wbuf[bufi][r][c0s]);
        }
    };
    stage(0, 0);   // weight DMA overlaps the tanh-heavy hs/ts staging below

    {   // stage hs/ts for BOTH n halves, 128 p-rows (tanh fused, f32->f16, XOR-swizzled cols)
        int p9 = t & 63; int s = t >> 6;      // s 0..3
        int nn = s >> 1; int c0 = (s & 1) * 32;
        int n = 2*g + nn;
        #pragma unroll
        for (int rr = 0; rr < 2; rr++) {
            int p = p9 + rr*64;
            int xw = (p & 7) << 3;
            int pr = p0 + p; if (pr > Mr-1) pr = Mr-1;
            const float* hp = hs + (size_t)pr*Hn + n*64 + c0;
            const float* tp = ts + (size_t)pr*Hn + n*64 + c0;
            #pragma unroll
            for (int b2 = 0; b2 < 2; b2++) {
                const float4* hp4 = (const float4*)(hp + b2*16);
                const float4* tp4 = (const float4*)(tp + b2*16);
                float4 x0=hp4[0], x1=hp4[1], x2=hp4[2], x3=hp4[3];
                uint4 oh, oh2;
                oh.x = pkrtz(tanhf(x0.x),tanhf(x0.y)); oh.y = pkrtz(tanhf(x0.z),tanhf(x0.w));
                oh.z = pkrtz(tanhf(x1.x),tanhf(x1.y)); oh.w = pkrtz(tanhf(x1.z),tanhf(x1.w));
                oh2.x = pkrtz(tanhf(x2.x),tanhf(x2.y)); oh2.y = pkrtz(tanhf(x2.z),tanhf(x2.w));
                oh2.z = pkrtz(tanhf(x3.x),tanhf(x3.y)); oh2.w = pkrtz(tanhf(x3.z),tanhf(x3.w));
                *(uint4*)&hsl[nn][p][(c0 + b2*16)     ^ xw] = oh;
                *(uint4*)&hsl[nn][p][(c0 + b2*16 + 8) ^ xw] = oh2;
                float4 y0=tp4[0], y1=tp4[1], y2=tp4[2], y3=tp4[3];
                uint4 ot, ot2;
                ot.x = pkrtz(tanhf(y0.x),tanhf(y0.y)); ot.y = pkrtz(tanhf(y0.z),tanhf(y0.w));
                ot.z = pkrtz(tanhf(y1.x),tanhf(y1.y)); ot.w = pkrtz(tanhf(y1.z),tanhf(y1.w));
                ot2.x = pkrtz(tanhf(y2.x),tanhf(y2.y)); ot2.y = pkrtz(tanhf(y2.z),tanhf(y2.w));
                ot2.z = pkrtz(tanhf(y3.x),tanhf(y3.y)); ot2.w = pkrtz(tanhf(y3.z),tanhf(y3.w));
                *(uint4*)&tsl[nn][p][(c0 + b2*16)     ^ xw] = ot;
                *(uint4*)&tsl[nn][p][(c0 + b2*16 + 8) ^ xw] = ot2;
            }
        }
    }
    __syncthreads();   // hs/ts staged AND chunk0 DMA complete (vmcnt drained at barrier)

    float4v acc[8];
    #pragma unroll
    for (int e = 0; e < 8; e++) acc[e] = (float4v)0.f;

    int buf = 0;
    #pragma unroll
    for (int nn = 0; nn < 2; nn++) {
        // ts fragments for this n, held across the 64 chunks
        half8 tsr0[8], tsr1[8];
        #pragma unroll
        for (int e = 0; e < 8; e++) {
            tsr0[e] = *(const half8*)&tsl[nn][e*16+ln][(q*8) ^ xr];
            tsr1[e] = *(const half8*)&tsl[nn][e*16+ln][(32 + q*8) ^ xr];
        }
        for (int ci = 0; ci < 64; ci++) {
            int cc = nn*64 + ci;
            if (cc + 1 < 128) stage(cc+1, buf^1);
            uint32 hd[8];
            #pragma unroll
            for (int e = 0; e < 8; e++) {
                uint32 hv = hsl[nn][e*16+ln][ci ^ xr];
                hd[e] = __builtin_amdgcn_perm(hv, hv, 0x01000100u);
            }
            #pragma unroll
            for (int c = 0; c < 2; c++) {
                half8 wf = *(const half8*)&wbuf[buf][w*16+ln][(c*32 + q*8) ^ xr];
                #pragma unroll
                for (int e = 0; e < 8; e++) {
                    half8 bfr = mulsplat(c ? tsr1[e] : tsr0[e], hd[e]);
                    acc[e] = __builtin_amdgcn_mfma_f32_16x16x32_f16(wf, bfr, acc[e], 0, 0, 0);
                }
            }
            __syncthreads();   // drains DMA for next buf; protects buf overwrite next iter
            buf ^= 1;
        }
    }
    #pragma unroll
    for (int e = 0; e < 8; e++) {
        int p = p0 + e*16 + ln;
        if (p >= Mr) continue;
        int dbase = d0 + w*16 + q*4;
        #pragma unroll
        for (int r = 0; r < 4; r++)
            atomicAdd(&pb[(size_t)p*Hn + dbase + r], acc[e][r]);
    }
}

// ---------------- back-end ----------------

__global__ __launch_bounds__(256) void k_featpp(const float* __restrict__ pairbl,
    const float* __restrict__ pos, const int* __restrict__ hts, float* __restrict__ fpp)
{
    int row = blockIdx.x; int t = threadIdx.x;
    int he = hts[row*2], te = hts[row*2+1];
    float* dst = fpp + (size_t)row*1024;
    if (t < 128) { dst[t] = pos[he*128 + t]; dst[896 + t] = pos[te*128 + t]; }
    for (int h = t; h < Hn; h += 256) dst[128 + h] = pairbl[(size_t)row*Hn + h];
}

// pair2 = tanh(pairT) + softmax(q@kT masked) @ v   (V read once; 3 d-chunks in regs)
__global__ __launch_bounds__(256) void k_graph(const float* __restrict__ q,
    const float* __restrict__ kT, const float* __restrict__ v, const float* __restrict__ vis,
    const float* __restrict__ pairT, float* __restrict__ pair2)
{
    int row = blockIdx.x; int b = row / Pn; int p = row % Pn;
    __shared__ float qs[Hn];
    __shared__ float sc[Pn];
    __shared__ float red[256];
    int t = threadIdx.x;
    for (int h = t; h < Hn; h += 256) qs[h] = q[(size_t)row*Hn + h];
    __syncthreads();
    for (int qq = t; qq < Pn; qq += 256) {
        const float* kcol = kT + (size_t)b*Hn*Pn + qq;
        float a = 0.f;
        for (int h = 0; h < Hn; h++) a += qs[h]*kcol[(size_t)h*Pn];
        a *= SCL;
        float ms = vis[((size_t)b*Pn + p)*Pn + qq];
        sc[qq] = (ms > 0.f) ? a : NEGV;
    }
    __syncthreads();
    float mx = -1e30f;
    for (int qq = t; qq < Pn; qq += 256) mx = fmaxf(mx, sc[qq]);
    red[t] = mx; __syncthreads();
    for (int s = 128; s > 0; s >>= 1) { if (t < s) red[t] = fmaxf(red[t], red[t+s]); __syncthreads(); }
    mx = red[0];
    __syncthreads();
    float ps = 0.f;
    for (int qq = t; qq < Pn; qq += 256) { float e2 = expf(sc[qq]-mx); sc[qq] = e2; ps += e2; }
    red[t] = ps; __syncthreads();
    for (int s = 128; s > 0; s >>= 1) { if (t < s) red[t] += red[t+s]; __syncthreads(); }
    float invs = 1.0f/red[0];
    __syncthreads();
    float a0 = 0.f, a1 = 0.f, a2 = 0.f;
    for (int qq = 0; qq < Pn; qq++) {
        float sv = sc[qq];
        const float* vr = v + ((size_t)b*Pn+qq)*Hn + t;
        a0 += sv*vr[0]; a1 += sv*vr[256]; a2 += sv*vr[512];
    }
    const float* pt = pairT + (size_t)row*Hn + t;
    float* o = pair2 + (size_t)row*Hn + t;
    o[0]   = tanhf(pt[0])   + a0*invs;
    o[256] = tanhf(pt[256]) + a1*invs;
    o[512] = tanhf(pt[512]) + a2*invs;
}

__global__ __launch_bounds__(256) void k_fillu(unsigned int* p, unsigned int v, int n){
    int i = blockIdx.x*256 + threadIdx.x;
    if (i < n) p[i] = v;
}

// ---------------- launch ----------------
extern "C" void kernel_launch(void* const* d_in, const int* in_sizes, int n_in,
                              void* d_out, int out_size, void* d_ws, size_t ws_size,
                              hipStream_t stream)
{
    const float* seq  = (const float*)d_in[0];
    const float* att  = (const float*)d_in[1];
    const int*   midx = (const int*)d_in[2];
    const float* mmask= (const float*)d_in[3];
    const int*   hts  = (const int*)d_in[4];
    const float* vis  = (const float*)d_in[5];
    const float* Wcq = (const float*)d_in[6];  const float* bcq = (const float*)d_in[7];
    const float* Weq = (const float*)d_in[8];  const float* beq = (const float*)d_in[9];
    const float* Whe = (const float*)d_in[10]; const float* bhe = (const float*)d_in[11];
    const float* Wte = (const float*)d_in[12]; const float* bte = (const float*)d_in[13];
    const float* Wbl = (const float*)d_in[14]; const float* bbl = (const float*)d_in[15];
    const float* Wpp = (const float*)d_in[16]; const float* bpp = (const float*)d_in[17];
    const float* Wgq = (const float*)d_in[18];
    const float* Wgk = (const float*)d_in[19];
    const float* Wgv = (const float*)d_in[20];
    const float* Wp1 = (const float*)d_in[21]; const float* bp1 = (const float*)d_in[22];
    const float* Wp2 = (const float*)d_in[23]; const float* bp2 = (const float*)d_in[24];
    const float* pos = (const float*)d_in[25];
    float* ws = (float*)d_ws;
    float* out = (float*)d_out;
    const float* nul = nullptr;
    float* nulw = nullptr;

    if (ws_size < 89505792ULL) {
        int n = out_size/2;
        k_fillu<<<(n+255)/256, 256, 0, stream>>>((unsigned int*)d_out, 0x476A476Au, n);
        return;
    }

    unsigned short* WCQt = (unsigned short*)(ws + oWCQ);
    unsigned short* WEQt = (unsigned short*)(ws + oWEQ);
    unsigned short* SEQt = (unsigned short*)(ws + oSEQT);
    unsigned short* WHEt = (unsigned short*)(ws + oWHE);
    unsigned short* WTEt = (unsigned short*)(ws + oWTE);
    unsigned short* WBLt = (unsigned short*)(ws + oWBL);
    unsigned short* WPPt = (unsigned short*)(ws + oWPP);
    unsigned short* WGQt = (unsigned short*)(ws + oWGQ);
    unsigned short* WP1t = (unsigned short*)(ws + oWP1);
    unsigned short* WP2t = (unsigned short*)(ws + oWP2);

    // ---- front-end ----
    k_ent_att<<<Bn*NEn*NHn, 256, 0, stream>>>(att, midx, mmask, ws + oEA);
    k_ent_emb<<<Bn*NEn*MMn, 256, 0, stream>>>(seq, midx, mmask, ws + oEE);
    k_htatt<<<Mr, 256, 0, stream>>>(ws + oEA, hts, ws + oHA);

    // Wcq/Weq + per-batch seq transposes (EA dead)
    {
        WT8 tb{}; tb.nd = 6;
        tb.d[0] = { Wcq, WCQt, 768, 128, 128, 0 };
        tb.d[1] = { Weq, WEQt, 768, 128, 128, 24 };
        for (int b = 0; b < 4; b++)
            tb.d[2+b] = { seq + (size_t)b*Cn*Hn, SEQt + (size_t)b*Hn*Cn, Cn, Hn, Hn, 48 + b*96 };
        k_wtr<<<432, 256, 0, stream>>>(tb);
    }
    // rs = ht_att @ seq[b]   (batched MFMA)
    k_gmfma<32,0><<<dim3(6,12,4), 256, 0, stream>>>(ws + oHA, nul, nul, Cn, 0, 0,
        SEQt, nul, ws + oRS, nulw, nulw, Pn, Hn, 0,
        (long)Pn*Cn, (long)Hn*Cn, (long)Pn*Hn);
    // htq = rs @ Wcq + bcq
    k_gmfma<4,0><<<dim3(24,2,1), 256, 0, stream>>>(ws + oRS, nul, nul, Hn, 0, 0,
        WCQt, bcq, ws + oHQ, nulw, nulw, Mr, QSn, 0, 0, 0, 0);
    // ent_key = ent_emb @ Weq + beq
    k_gmfma<4,0><<<dim3(29,2,1), 256, 0, stream>>>(ws + oEE, nul, nul, Hn, 0, 0,
        WEQt, beq, ws + oEK, nulw, nulw, Bn*NEn*MMn, QSn, 0, 0, 0, 0);
    k_select<<<dim3(Mr,2), 256, 0, stream>>>(ws + oHQ, ws + oEK, ws + oEE,
        mmask, hts, ws + oSH, ws + oST);

    // Whe/Wte transposes (EA/EE/EK/HQ dead)
    {
        WT8 tb{}; tb.nd = 2;
        tb.d[0] = { Whe, WHEt, 1536, 768, 768, 0 };
        tb.d[1] = { Wte, WTEt, 1536, 768, 768, 288 };
        k_wtr<<<576, 256, 0, stream>>>(tb);
    }
    // bias-init hs/ts/pb in one pass (contiguous), then atomic k-split GEMMs (raw, tanh at consumers)
    k_binit3<<<(3*Mr*Hn)/256, 256, 0, stream>>>(bhe, bte, bbl, ws + o_HS);
    k_gmfma<1,0><<<dim3(24,12,3), 256, 0, stream>>>(ws + oSH, ws + oRS, nul, Hn, Hn, 0,
        WHEt, nul, ws + o_HS, nulw, nulw, Mr, Hn, 512, 0, 0, 0);
    k_gmfma<1,0><<<dim3(24,12,3), 256, 0, stream>>>(ws + oST, ws + oRS, nul, Hn, Hn, 0,
        WTEt, nul, ws + o_TS, nulw, nulw, Mr, Hn, 512, 0, 0, 0);

    // bilinear: Wbl transpose (all X dead), MFMA v10 (128-p tile, gl_lds staging)
    {
        WT8 tb{}; tb.nd = 1;
        tb.d[0] = { Wbl, WBLt, 49152, 768, 768, 0 };
        k_wtr<<<9216, 256, 0, stream>>>(tb);
    }
    k_blmfma<<<dim3(12,12,6), 256, 0, stream>>>(ws + o_HS, ws + o_TS, WBLt, ws + o_PB);

    k_featpp<<<Mr, 256, 0, stream>>>(ws + o_PB, pos, hts, ws + oFP);

    // late weight transposes (WblT dead)
    {
        WT8 tb{}; tb.nd = 6;
        tb.d[0] = { Wpp, WPPt, 1024, 768, 768, 0 };
        tb.d[1] = { Wgq, WGQt, 768, 768, 768, 192 };
        tb.d[2] = { Wgk, (unsigned short*)(ws + oWGK), 768, 768, 768, 336 };
        tb.d[3] = { Wgv, (unsigned short*)(ws + oWGV), 768, 768, 768, 480 };
        tb.d[4] = { Wp1, WP1t, 2304, 768, 768, 624 };
        tb.d[5] = { Wp2, WP2t, 768, 97, 128, 1056 };
        k_wtr<<<1080, 256, 0, stream>>>(tb);
    }
    // pairT-acc = fpp @ Wpp + bpp  (raw; tanh at consumers)
    k_binit<<<(Mr*Hn)/256, 256, 0, stream>>>(bpp, ws + oPT, Hn);
    k_gmfma<1,0><<<dim3(24,12,2), 256, 0, stream>>>(ws + oFP, nul, nul, 1024, 0, 0,
        WPPt, nul, ws + oPT, nulw, nulw, Mr, Hn, 512, 0, 0, 0);
    // fused q|kT|v = tanh(pairT) @ [Wgq|Wgk|Wgv]  (weights contiguous, N=2304)
    k_gmfma<16,1><<<dim3(24,36,1), 256, 0, stream>>>(ws + oPT, nul, nul, Hn, 0, 0,
        WGQt, nul, ws + oQ, ws + oKT, ws + oV, Mr, 3*Hn, 0, 0, 0, 0);
    k_graph<<<Mr, 256, 0, stream>>>(ws + oQ, ws + oKT, ws + oV, vis, ws + oPT, ws + oP2);
    // t1-acc = [tanh(hs)|tanh(ts)|pair2] @ Wp1 + bp1  (raw; tanh at final gemm)
    k_binit<<<(Mr*Hn)/256, 256, 0, stream>>>(bp1, ws + oT1, Hn);
    k_gmfma<1,3><<<dim3(24,12,3), 256, 0, stream>>>(ws + o_HS, ws + o_TS, ws + oP2,
        Hn, Hn, Hn, WP1t, nul, ws + oT1, nulw, nulw, Mr, Hn, 768, 0, 0, 0);
    // logits = tanh(t1) @ Wp2 + bp2
    k_gmfma<4,1><<<dim3(24,2,1), 256, 0, stream>>>(ws + oT1, nul, nul, Hn, 0, 0,
        WP2t, bp2, out, nulw, nulw, Mr, 97, 0, 0, 0, 0);
}

// Round 10
// 908.341 us; speedup vs baseline: 1.1654x; 1.1424x over previous
//
#include <hip/hip_runtime.h>
#include <hip/hip_bf16.h>

#define Bn   4
#define Cn   512
#define Hn   768
#define NHn  12
#define NEn  20
#define MMn  23
#define Pn   380
#define Mr   1520     // B*P
#define QSn  128
#define NEGV (-10000.0f)
#define SCL  0.036084391824351615f   // 1/sqrt(768)

typedef unsigned int uint32;
typedef __attribute__((ext_vector_type(4))) float float4v;
typedef __attribute__((ext_vector_type(2))) _Float16 half2v;
typedef __attribute__((ext_vector_type(2))) __fp16 fp16x2;
typedef __attribute__((ext_vector_type(8))) _Float16 half8;

// f32 -> f16 single element (RNE, v_cvt_f16_f32)
__device__ __forceinline__ unsigned short f2h(float f){
    return __builtin_bit_cast(unsigned short, (_Float16)f);
}
// pack 2 f32 -> 2 f16 in one v_cvt_pkrtz_f16_f32
__device__ __forceinline__ uint32 pkrtz(float a, float b){
    fp16x2 h = __builtin_amdgcn_cvt_pkrtz(a, b);
    return __builtin_bit_cast(uint32, h);
}
// half8 * splat(half2) elementwise -> 4x v_pk_mul_f16
__device__ __forceinline__ half8 mulsplat(half8 a, uint32 hd){
    half2v s = __builtin_bit_cast(half2v, hd);
    union { half8 h; half2v c[4]; } u, v;
    u.h = a;
    #pragma unroll
    for (int i = 0; i < 4; i++) v.c[i] = u.c[i] * s;
    return v.h;
}
// 16B global -> LDS direct (DMA; dest must be wave-uniform base + lane*16)
__device__ __forceinline__ void gl_lds16(const unsigned short* g, unsigned short* l){
    __builtin_amdgcn_global_load_lds(
        (const __attribute__((address_space(1))) void*)g,
        (__attribute__((address_space(3))) void*)l, 16, 0, 0);
}

// ---------------- ws layout (float offsets) ----------------
static const size_t o_HS = 0;          // hs-acc [Mr][768]  (raw, tanh at consumers)
static const size_t o_TS = 1167360;    // ts-acc
static const size_t o_PB = 2334720;    // bilinear acc
static const size_t Xo   = 3502080;    // time-shared region, 18,874,368 floats
// early scratch
static const size_t oEA = Xo;           // 491520
static const size_t oEE = Xo+491520;    // 1413120
static const size_t oEK = Xo+1904640;   // 235520
static const size_t oHA = Xo+2140160;   // 778240
static const size_t oHQ = Xo+2918400;   // 194560
static const size_t oSH = Xo+3112960;   // 1167360
static const size_t oST = Xo+4280320;   // 1167360
static const size_t oRS = Xo+5447680;   // 1167360
static const size_t oSEQT = Xo+6615040; // seqT f16 [B][768][512] = 786432 f
// weight^T f16 regions (float offsets; cast to ushort*)
static const size_t oWCQ = Xo;          // over dead EA, 49152 f
static const size_t oWEQ = Xo+49152;    // 49152 f
static const size_t oWHE = Xo;          // after select (EA/EE dead), 589824 f
static const size_t oWTE = Xo+589824;   // 589824 f
static const size_t oWBL = Xo;          // after ts-gmfma, all of X
// late scratch (after blmfma, over dead WblT)
static const size_t oFP = Xo;           // 1556480
static const size_t oPT = Xo+1556480;
static const size_t oQ  = Xo+2723840;   // q f32 [1520][768]
static const size_t oKT = Xo+3891200;   // K16 f16 [1520][768] (583680 f) | P f32 [4][380][384] (583680 f)
static const size_t oP_ = oKT+583680;
static const size_t oV  = Xo+5058560;   // Vt16 f16 [4][768][384] = 589824 f
static const size_t oP2 = Xo+6225920;   // S f32 [4][380][380] then PV/pair2 [1520][768]
static const size_t oT1 = Xo+7393280;   // ends Xo+8560640
static const size_t oWPP = Xo+8560640;  // 393216 f
static const size_t oWGQ = Xo+8953856;  // 294912 f  (WGQ|WGK|WGV contiguous -> fused qkv)
static const size_t oWGK = Xo+9248768;
static const size_t oWGV = Xo+9543680;
static const size_t oWP1 = Xo+9838592;  // 884736 f
static const size_t oWP2 = Xo+10723328; // 49152 f
// total = 22,376,448 floats = 89,505,792 B

// ---------------- front-end ----------------

__global__ __launch_bounds__(256) void k_ent_att(const float* __restrict__ att,
    const int* __restrict__ midx, const float* __restrict__ mmask, float* __restrict__ ea)
{
    int x = blockIdx.x;
    int nh = x % NHn; int e = (x / NHn) % NEn; int b = x / (NHn * NEn);
    __shared__ int   sidx[MMn];
    __shared__ float smsk[MMn];
    int t = threadIdx.x;
    if (t < MMn) { sidx[t] = midx[(b*NEn+e)*MMn + t]; smsk[t] = mmask[(b*NEn+e)*MMn + t]; }
    __syncthreads();
    float cnt = 0.f;
    for (int m = 0; m < MMn; m++) cnt += smsk[m];
    for (int c = t; c < Cn; c += 256) {
        float acc = 0.f;
        for (int m = 0; m < MMn; m++)
            acc += smsk[m] * att[((size_t)(b*NHn+nh)*Cn + sidx[m])*Cn + c];
        ea[(size_t)x*Cn + c] = acc / cnt;
    }
}

__global__ __launch_bounds__(256) void k_ent_emb(const float* __restrict__ seq,
    const int* __restrict__ midx, const float* __restrict__ mmask, float* __restrict__ ee)
{
    int x = blockIdx.x;
    int b = x / (NEn*MMn);
    int idx = midx[x]; float msk = mmask[x];
    int t = threadIdx.x;
    for (int h = t; h < Hn; h += 256)
        ee[(size_t)x*Hn + h] = msk * seq[((size_t)b*Cn + idx)*Hn + h];
}

__global__ __launch_bounds__(256) void k_htatt(const float* __restrict__ ea,
    const int* __restrict__ hts, float* __restrict__ hta)
{
    int row = blockIdx.x; int b = row / Pn;
    int he = hts[row*2], te = hts[row*2+1];
    __shared__ float sc[Cn];
    __shared__ float red[256];
    int t = threadIdx.x;
    const float* eah = ea + (size_t)(b*NEn+he)*NHn*Cn;
    const float* eat = ea + (size_t)(b*NEn+te)*NHn*Cn;
    for (int c = t; c < Cn; c += 256) {
        float a = 0.f;
        for (int nh = 0; nh < NHn; nh++) a += eah[nh*Cn+c]*eat[nh*Cn+c];
        sc[c] = a * (1.0f/NHn);
    }
    __syncthreads();
    float ps = sc[t] + sc[t+256];
    red[t] = ps; __syncthreads();
    for (int s = 128; s > 0; s >>= 1) { if (t < s) red[t] += red[t+s]; __syncthreads(); }
    float inv = 1.0f/(red[0] + 1e-5f);
    for (int c = t; c < Cn; c += 256) hta[(size_t)row*Cn + c] = sc[c]*inv;
}

__global__ __launch_bounds__(256) void k_select(const float* __restrict__ htq,
    const float* __restrict__ ekey, const float* __restrict__ ee,
    const float* __restrict__ mmask, const int* __restrict__ hts,
    float* __restrict__ selh, float* __restrict__ selt)
{
    int row = blockIdx.x; int side = blockIdx.y;
    int b = row / Pn;
    int e = hts[row*2 + side];
    __shared__ float qv[QSn];
    __shared__ float gsc[MMn];
    __shared__ float ew[MMn];
    int t = threadIdx.x;
    if (t < QSn) qv[t] = htq[(size_t)row*QSn + t];
    __syncthreads();
    if (t < MMn) {
        const float* kr = ekey + ((size_t)(b*NEn+e)*MMn + t)*QSn;
        float g = 0.f;
        for (int qq = 0; qq < QSn; qq++) g += qv[qq]*kr[qq];
        g *= SCL;
        float msk = mmask[(b*NEn+e)*MMn + t];
        gsc[t] = (msk > 0.f) ? g : NEGV;
    }
    __syncthreads();
    float mx = -1e30f;
    for (int m = 0; m < MMn; m++) mx = fmaxf(mx, gsc[m]);
    if (t < MMn) ew[t] = expf(gsc[t] - mx);
    __syncthreads();
    float s = 0.f;
    for (int m = 0; m < MMn; m++) s += ew[m];
    float invs = 1.0f/s;
    float* dst = side ? selt : selh;
    const float* eb = ee + (size_t)(b*NEn+e)*MMn*Hn;
    for (int h = t; h < Hn; h += 256) {
        float o = 0.f;
        for (int m = 0; m < MMn; m++) o += ew[m]*eb[(size_t)m*Hn + h];
        dst[(size_t)row*Hn + h] = o*invs;
    }
}

// ---------------- weight transpose/convert: W[K][N] f32 -> Wt[Npad][K] f16 ----------------
struct WD { const float* src; unsigned short* dst; int K; int N; int Npad; int t0; };
struct WT8 { WD d[8]; int nd; };

__global__ __launch_bounds__(256) void k_wtr(WT8 tab)
{
    int b = blockIdx.x;
    int i = 0;
    while (i+1 < tab.nd && b >= tab.d[i+1].t0) i++;
    WD d = tab.d[i];
    int tile = b - d.t0;
    int ktiles = d.K >> 6;
    int kt = tile % ktiles, nt = tile / ktiles;
    int k0 = kt*64, n0 = nt*64;
    __shared__ __align__(16) unsigned short tl[64][72];
    int t = threadIdx.x;
    int nl = t & 63, rq = t >> 6;
    #pragma unroll
    for (int r = 0; r < 16; r++) {
        int kl = r*4 + rq;
        float v = (n0+nl < d.N) ? d.src[(size_t)(k0+kl)*d.N + n0 + nl] : 0.f;
        tl[nl][kl] = f2h(v);
    }
    __syncthreads();
    int nn2 = t >> 2, kk0 = (t & 3) * 16;
    uint4 a = *(const uint4*)&tl[nn2][kk0];
    uint4 bq = *(const uint4*)&tl[nn2][kk0+8];
    uint4* dst = (uint4*)&d.dst[(size_t)(n0+nn2)*d.K + k0 + kk0];
    dst[0] = a; dst[1] = bq;
}

// ---------------- generic MFMA GEMM (fp16 datapath) ----------------
// out[M][N] = A[M][K](f32, up to 3 segments) @ Wt^T (Wt f16 [Npad][K])
// MODE bits: 1=atomic accumulate (k-split over z; bias pre-init), 4=+bias,
//            16=qkv routing (out=q f32, out2=K f16 rows, out3=V f16 transposed [b][768][384]),
//            32=batched over z (aStride/wStride/oStride)
// TM: tanh applied to A-segment s when (TM>>s)&1
template<int MODE, int TM>
__global__ __launch_bounds__(256,4) void k_gmfma(
    const float* __restrict__ A0, const float* __restrict__ A1, const float* __restrict__ A2,
    int KA, int KB, int KC,
    const unsigned short* __restrict__ Wt,
    const float* __restrict__ bias, float* __restrict__ out,
    float* __restrict__ out2, float* __restrict__ out3,
    int Mtot, int N, int kchunk,
    long aStride, long wStride, long oStride)
{
    __shared__ __align__(16) unsigned short sa[64][72];
    __shared__ __align__(16) unsigned short sw[64][72];
    int t = threadIdx.x;
    int K = KA + KB + KC;
    int row0 = blockIdx.x * 64;
    int n0 = blockIdx.y * 64;
    int bz = blockIdx.z;
    const float* Ab = A0; const unsigned short* W = Wt; float* O = out;
    if (MODE & 32) { Ab += (size_t)bz*aStride; W += (size_t)bz*wStride; O += (size_t)bz*oStride; }
    int k0 = 0, k1 = K;
    if (MODE & 1) { k0 = bz*kchunk; k1 = k0 + kchunk; }
    int lane = t & 63, w = t >> 6, ln = lane & 15, q = lane >> 4;
    int sr = t >> 2;
    int sk = (t & 3) * 16;
    int rA = row0 + sr; if (rA > Mtot-1) rA = Mtot-1;

    float4v acc[4];
    #pragma unroll
    for (int mt = 0; mt < 4; mt++) acc[mt] = (float4v)0.f;

    for (int kk = k0; kk < k1; kk += 64) {
        const float* src; int kloc, Kl, seg;
        if (kk < KA)            { src = Ab; kloc = kk;          Kl = KA; seg = 0; }
        else if (kk < KA + KB)  { src = A1; kloc = kk - KA;     Kl = KB; seg = 1; }
        else                    { src = A2; kloc = kk - KA - KB; Kl = KC; seg = 2; }
        const float* ap = &src[(size_t)rA*Kl + kloc + sk];
        float4 v0 = ((const float4*)ap)[0];
        float4 v1 = ((const float4*)ap)[1];
        float4 v2 = ((const float4*)ap)[2];
        float4 v3 = ((const float4*)ap)[3];
        if (TM && ((TM >> seg) & 1)) {
            v0.x = tanhf(v0.x); v0.y = tanhf(v0.y); v0.z = tanhf(v0.z); v0.w = tanhf(v0.w);
            v1.x = tanhf(v1.x); v1.y = tanhf(v1.y); v1.z = tanhf(v1.z); v1.w = tanhf(v1.w);
            v2.x = tanhf(v2.x); v2.y = tanhf(v2.y); v2.z = tanhf(v2.z); v2.w = tanhf(v2.w);
            v3.x = tanhf(v3.x); v3.y = tanhf(v3.y); v3.z = tanhf(v3.z); v3.w = tanhf(v3.w);
        }
        const uint4* gw = (const uint4*)&W[(size_t)(n0+sr)*K + kk + sk];
        uint4 w0 = gw[0], w1 = gw[1];
        uint4 pa, pb;
        pa.x = pkrtz(v0.x, v0.y); pa.y = pkrtz(v0.z, v0.w);
        pa.z = pkrtz(v1.x, v1.y); pa.w = pkrtz(v1.z, v1.w);
        pb.x = pkrtz(v2.x, v2.y); pb.y = pkrtz(v2.z, v2.w);
        pb.z = pkrtz(v3.x, v3.y); pb.w = pkrtz(v3.z, v3.w);
        *(uint4*)&sa[sr][sk]   = pa;
        *(uint4*)&sa[sr][sk+8] = pb;
        *(uint4*)&sw[sr][sk]   = w0;
        *(uint4*)&sw[sr][sk+8] = w1;
        __syncthreads();
        half8 b0 = *(const half8*)&sw[w*16+ln][q*8];
        half8 b1 = *(const half8*)&sw[w*16+ln][32 + q*8];
        #pragma unroll
        for (int mt = 0; mt < 4; mt++) {
            half8 a0 = *(const half8*)&sa[mt*16+ln][q*8];
            half8 a1 = *(const half8*)&sa[mt*16+ln][32 + q*8];
            acc[mt] = __builtin_amdgcn_mfma_f32_16x16x32_f16(a0, b0, acc[mt], 0, 0, 0);
            acc[mt] = __builtin_amdgcn_mfma_f32_16x16x32_f16(a1, b1, acc[mt], 0, 0, 0);
        }
        __syncthreads();
    }
    // D: row(m) = (lane>>4)*4+r (A row), col(n) = lane&15 (W row)
    int nn = n0 + w*16 + ln;
    if (MODE & 16) {
        int sg = nn / Hn; int nl = nn - sg*Hn;
        #pragma unroll
        for (int mt = 0; mt < 4; mt++) {
            #pragma unroll
            for (int r = 0; r < 4; r++) {
                int row = row0 + mt*16 + q*4 + r;
                if (row >= Mtot) continue;
                float val = acc[mt][r];
                if (sg == 0)      out [(size_t)row*Hn + nl] = val;
                else if (sg == 1) ((unsigned short*)out2)[(size_t)row*Hn + nl] = f2h(val);
                else {
                    int bb = row / Pn, pp = row % Pn;
                    ((unsigned short*)out3)[((size_t)bb*Hn + nl)*384 + pp] = f2h(val);
                }
            }
        }
        return;
    }
    if (nn >= N) return;
    float bv = (MODE & 4) ? bias[nn] : 0.f;
    #pragma unroll
    for (int mt = 0; mt < 4; mt++) {
        #pragma unroll
        for (int r = 0; r < 4; r++) {
            int row = row0 + mt*16 + q*4 + r;
            if (row >= Mtot) continue;
            float val = acc[mt][r];
            if (MODE & 1) atomicAdd(&O[(size_t)row*N + nn], val);
            else          O[(size_t)row*N + nn] = val + bv;
        }
    }
}

__global__ __launch_bounds__(256) void k_binit(const float* __restrict__ bias,
    float* __restrict__ o, int N)
{
    int idx = blockIdx.x*256 + threadIdx.x;
    o[idx] = bias[idx % N];
}

__global__ __launch_bounds__(256) void k_binit3(const float* __restrict__ b0,
    const float* __restrict__ b1, const float* __restrict__ b2, float* __restrict__ o)
{
    int idx = blockIdx.x*256 + threadIdx.x;   // < 3*Mr*Hn
    int r = idx / (Mr*Hn);
    const float* bb = (r == 0) ? b0 : ((r == 1) ? b1 : b2);
    o[idx] = bb[idx % Hn];
}

// ---------------- bilinear MFMA v8 (best measured): global_load_lds weight staging ----------------
__global__ __launch_bounds__(256,3) void k_blmfma(const float* __restrict__ hs,
    const float* __restrict__ ts, const unsigned short* __restrict__ Wt,
    float* __restrict__ pb)
{
    __shared__ __align__(16) unsigned short hsl[2][64][64];
    __shared__ __align__(16) unsigned short tsl[2][64][64];
    __shared__ __align__(16) unsigned short wbuf[2][64][64];
    int t = threadIdx.x;
    int bid = blockIdx.x + 24*(blockIdx.y + 12*(int)blockIdx.z);
    int sb = (bid & 7)*216 + (bid >> 3);
    int p_t = sb % 24; int r2 = sb / 24;     // r2 0..71
    int p0 = p_t * 64;                        // 24 p-tiles
    int d0 = (r2 % 12) * 64;                  // 12 d-tiles
    int g  = r2 / 12;                         // 6 -> n = 2g, 2g+1
    int lane = t & 63, w = t >> 6, ln = lane & 15, q = lane >> 4;
    int xr = (ln & 7) << 3;

    const unsigned short* Wd = Wt + (size_t)d0*49152;
    auto stage = [&](int cc, int bufi){
        int n2 = 2*g + (cc >> 6);
        size_t kb = (size_t)n2*4096 + (size_t)(cc & 63)*64;
        #pragma unroll
        for (int pass = 0; pass < 2; pass++) {
            int r = pass*32 + (t >> 3);
            int c0s = (t & 7) * 8;
            gl_lds16(Wd + (size_t)r*49152 + kb + (c0s ^ ((r & 7) << 3)),
                     &wbuf[bufi][r][c0s]);
        }
    };
    stage(0, 0);

    {   // stage hs/ts for BOTH n halves (tanh fused, f32->f16, XOR-swizzled cols)
        int p = t & 63; int s = t >> 6;
        int nn = s >> 1; int c0 = (s & 1) * 32;
        int xw = (p & 7) << 3;
        int pr = p0 + p; if (pr > Mr-1) pr = Mr-1;
        int n = 2*g + nn;
        const float* hp = hs + (size_t)pr*Hn + n*64 + c0;
        const float* tp = ts + (size_t)pr*Hn + n*64 + c0;
        #pragma unroll
        for (int b2 = 0; b2 < 2; b2++) {
            const float4* hp4 = (const float4*)(hp + b2*16);
            const float4* tp4 = (const float4*)(tp + b2*16);
            float4 x0=hp4[0], x1=hp4[1], x2=hp4[2], x3=hp4[3];
            uint4 oh, oh2;
            oh.x = pkrtz(tanhf(x0.x),tanhf(x0.y)); oh.y = pkrtz(tanhf(x0.z),tanhf(x0.w));
            oh.z = pkrtz(tanhf(x1.x),tanhf(x1.y)); oh.w = pkrtz(tanhf(x1.z),tanhf(x1.w));
            oh2.x = pkrtz(tanhf(x2.x),tanhf(x2.y)); oh2.y = pkrtz(tanhf(x2.z),tanhf(x2.w));
            oh2.z = pkrtz(tanhf(x3.x),tanhf(x3.y)); oh2.w = pkrtz(tanhf(x3.z),tanhf(x3.w));
            *(uint4*)&hsl[nn][p][(c0 + b2*16)     ^ xw] = oh;
            *(uint4*)&hsl[nn][p][(c0 + b2*16 + 8) ^ xw] = oh2;
            float4 y0=tp4[0], y1=tp4[1], y2=tp4[2], y3=tp4[3];
            uint4 ot, ot2;
            ot.x = pkrtz(tanhf(y0.x),tanhf(y0.y)); ot.y = pkrtz(tanhf(y0.z),tanhf(y0.w));
            ot.z = pkrtz(tanhf(y1.x),tanhf(y1.y)); ot.w = pkrtz(tanhf(y1.z),tanhf(y1.w));
            ot2.x = pkrtz(tanhf(y2.x),tanhf(y2.y)); ot2.y = pkrtz(tanhf(y2.z),tanhf(y2.w));
            ot2.z = pkrtz(tanhf(y3.x),tanhf(y3.y)); ot2.w = pkrtz(tanhf(y3.z),tanhf(y3.w));
            *(uint4*)&tsl[nn][p][(c0 + b2*16)     ^ xw] = ot;
            *(uint4*)&tsl[nn][p][(c0 + b2*16 + 8) ^ xw] = ot2;
        }
    }
    __syncthreads();

    float4v acc[4];
    #pragma unroll
    for (int e = 0; e < 4; e++) acc[e] = (float4v)0.f;

    int buf = 0;
    #pragma unroll
    for (int nn = 0; nn < 2; nn++) {
        half8 tsr0[4], tsr1[4];
        #pragma unroll
        for (int e = 0; e < 4; e++) {
            tsr0[e] = *(const half8*)&tsl[nn][e*16+ln][(q*8) ^ xr];
            tsr1[e] = *(const half8*)&tsl[nn][e*16+ln][(32 + q*8) ^ xr];
        }
        for (int ci = 0; ci < 64; ci++) {
            int cc = nn*64 + ci;
            if (cc + 1 < 128) stage(cc+1, buf^1);
            uint32 hd[4];
            #pragma unroll
            for (int e = 0; e < 4; e++) {
                uint32 hv = hsl[nn][e*16+ln][ci ^ xr];
                hd[e] = __builtin_amdgcn_perm(hv, hv, 0x01000100u);
            }
            #pragma unroll
            for (int c = 0; c < 2; c++) {
                half8 wf = *(const half8*)&wbuf[buf][w*16+ln][(c*32 + q*8) ^ xr];
                #pragma unroll
                for (int e = 0; e < 4; e++) {
                    half8 bfr = mulsplat(c ? tsr1[e] : tsr0[e], hd[e]);
                    acc[e] = __builtin_amdgcn_mfma_f32_16x16x32_f16(wf, bfr, acc[e], 0, 0, 0);
                }
            }
            __syncthreads();
            buf ^= 1;
        }
    }
    #pragma unroll
    for (int e = 0; e < 4; e++) {
        int p = p0 + e*16 + ln;
        if (p >= Mr) continue;
        int dbase = d0 + w*16 + q*4;
        #pragma unroll
        for (int r = 0; r < 4; r++)
            atomicAdd(&pb[(size_t)p*Hn + dbase + r], acc[e][r]);
    }
}

// ---------------- back-end ----------------

__global__ __launch_bounds__(256) void k_featpp(const float* __restrict__ pairbl,
    const float* __restrict__ pos, const int* __restrict__ hts, float* __restrict__ fpp)
{
    int row = blockIdx.x; int t = threadIdx.x;
    int he = hts[row*2], te = hts[row*2+1];
    float* dst = fpp + (size_t)row*1024;
    if (t < 128) { dst[t] = pos[he*128 + t]; dst[896 + t] = pos[te*128 + t]; }
    for (int h = t; h < Hn; h += 256) dst[128 + h] = pairbl[(size_t)row*Hn + h];
}

// masked softmax: S[b][380][380] (raw q.k) -> P f32 [b][380][384] (pad cols zeroed)
__global__ __launch_bounds__(256) void k_smax(const float* __restrict__ S,
    const float* __restrict__ vis, float* __restrict__ P)
{
    int row = blockIdx.x; int b = row / Pn; int p = row % Pn;
    __shared__ float sc[Pn];
    __shared__ float red[256];
    int t = threadIdx.x;
    const float* Sr = S + (size_t)b*Pn*Pn + (size_t)p*Pn;
    const float* vr = vis + ((size_t)b*Pn + p)*Pn;
    float mx0 = -1e30f;
    for (int qq = t; qq < Pn; qq += 256) {
        float a = Sr[qq] * SCL;
        a = (vr[qq] > 0.f) ? a : NEGV;
        sc[qq] = a; mx0 = fmaxf(mx0, a);
    }
    red[t] = mx0; __syncthreads();
    for (int s = 128; s > 0; s >>= 1) { if (t < s) red[t] = fmaxf(red[t], red[t+s]); __syncthreads(); }
    float mx = red[0]; __syncthreads();
    float ps = 0.f;
    for (int qq = t; qq < Pn; qq += 256) { float e = expf(sc[qq]-mx); sc[qq] = e; ps += e; }
    red[t] = ps; __syncthreads();
    for (int s = 128; s > 0; s >>= 1) { if (t < s) red[t] += red[t+s]; __syncthreads(); }
    float inv = 1.0f/red[0];
    __syncthreads();
    float* Pr = P + (size_t)b*Pn*384 + (size_t)p*384;
    for (int qq = t; qq < Pn; qq += 256) Pr[qq] = sc[qq]*inv;
    if (t < 4) Pr[Pn + t] = 0.f;
}

// pair2 = tanh(pairT) + PV   (in-place over PV buffer)
__global__ __launch_bounds__(256) void k_resid(const float* __restrict__ pt, float* __restrict__ p2)
{
    size_t i = (size_t)blockIdx.x*256 + threadIdx.x;   // total Mr*Hn
    p2[i] = tanhf(pt[i]) + p2[i];
}

__global__ __launch_bounds__(256) void k_fillu(unsigned int* p, unsigned int v, int n){
    int i = blockIdx.x*256 + threadIdx.x;
    if (i < n) p[i] = v;
}

// ---------------- launch ----------------
extern "C" void kernel_launch(void* const* d_in, const int* in_sizes, int n_in,
                              void* d_out, int out_size, void* d_ws, size_t ws_size,
                              hipStream_t stream)
{
    const float* seq  = (const float*)d_in[0];
    const float* att  = (const float*)d_in[1];
    const int*   midx = (const int*)d_in[2];
    const float* mmask= (const float*)d_in[3];
    const int*   hts  = (const int*)d_in[4];
    const float* vis  = (const float*)d_in[5];
    const float* Wcq = (const float*)d_in[6];  const float* bcq = (const float*)d_in[7];
    const float* Weq = (const float*)d_in[8];  const float* beq = (const float*)d_in[9];
    const float* Whe = (const float*)d_in[10]; const float* bhe = (const float*)d_in[11];
    const float* Wte = (const float*)d_in[12]; const float* bte = (const float*)d_in[13];
    const float* Wbl = (const float*)d_in[14]; const float* bbl = (const float*)d_in[15];
    const float* Wpp = (const float*)d_in[16]; const float* bpp = (const float*)d_in[17];
    const float* Wgq = (const float*)d_in[18];
    const float* Wgk = (const float*)d_in[19];
    const float* Wgv = (const float*)d_in[20];
    const float* Wp1 = (const float*)d_in[21]; const float* bp1 = (const float*)d_in[22];
    const float* Wp2 = (const float*)d_in[23]; const float* bp2 = (const float*)d_in[24];
    const float* pos = (const float*)d_in[25];
    float* ws = (float*)d_ws;
    float* out = (float*)d_out;
    const float* nul = nullptr;
    float* nulw = nullptr;

    if (ws_size < 89505792ULL) {
        int n = out_size/2;
        k_fillu<<<(n+255)/256, 256, 0, stream>>>((unsigned int*)d_out, 0x476A476Au, n);
        return;
    }

    unsigned short* WCQt = (unsigned short*)(ws + oWCQ);
    unsigned short* WEQt = (unsigned short*)(ws + oWEQ);
    unsigned short* SEQt = (unsigned short*)(ws + oSEQT);
    unsigned short* WHEt = (unsigned short*)(ws + oWHE);
    unsigned short* WTEt = (unsigned short*)(ws + oWTE);
    unsigned short* WBLt = (unsigned short*)(ws + oWBL);
    unsigned short* WPPt = (unsigned short*)(ws + oWPP);
    unsigned short* WGQt = (unsigned short*)(ws + oWGQ);
    unsigned short* WP1t = (unsigned short*)(ws + oWP1);
    unsigned short* WP2t = (unsigned short*)(ws + oWP2);
    unsigned short* K16  = (unsigned short*)(ws + oKT);
    unsigned short* Vt16 = (unsigned short*)(ws + oV);

    // ---- front-end ----
    k_ent_att<<<Bn*NEn*NHn, 256, 0, stream>>>(att, midx, mmask, ws + oEA);
    k_ent_emb<<<Bn*NEn*MMn, 256, 0, stream>>>(seq, midx, mmask, ws + oEE);
    k_htatt<<<Mr, 256, 0, stream>>>(ws + oEA, hts, ws + oHA);

    // Wcq/Weq + per-batch seq transposes (EA dead)
    {
        WT8 tb{}; tb.nd = 6;
        tb.d[0] = { Wcq, WCQt, 768, 128, 128, 0 };
        tb.d[1] = { Weq, WEQt, 768, 128, 128, 24 };
        for (int b = 0; b < 4; b++)
            tb.d[2+b] = { seq + (size_t)b*Cn*Hn, SEQt + (size_t)b*Hn*Cn, Cn, Hn, Hn, 48 + b*96 };
        k_wtr<<<432, 256, 0, stream>>>(tb);
    }
    // rs = ht_att @ seq[b]   (batched MFMA)
    k_gmfma<32,0><<<dim3(6,12,4), 256, 0, stream>>>(ws + oHA, nul, nul, Cn, 0, 0,
        SEQt, nul, ws + oRS, nulw, nulw, Pn, Hn, 0,
        (long)Pn*Cn, (long)Hn*Cn, (long)Pn*Hn);
    // htq = rs @ Wcq + bcq
    k_gmfma<4,0><<<dim3(24,2,1), 256, 0, stream>>>(ws + oRS, nul, nul, Hn, 0, 0,
        WCQt, bcq, ws + oHQ, nulw, nulw, Mr, QSn, 0, 0, 0, 0);
    // ent_key = ent_emb @ Weq + beq
    k_gmfma<4,0><<<dim3(29,2,1), 256, 0, stream>>>(ws + oEE, nul, nul, Hn, 0, 0,
        WEQt, beq, ws + oEK, nulw, nulw, Bn*NEn*MMn, QSn, 0, 0, 0, 0);
    k_select<<<dim3(Mr,2), 256, 0, stream>>>(ws + oHQ, ws + oEK, ws + oEE,
        mmask, hts, ws + oSH, ws + oST);

    // Whe/Wte transposes (EA/EE/EK/HQ dead)
    {
        WT8 tb{}; tb.nd = 2;
        tb.d[0] = { Whe, WHEt, 1536, 768, 768, 0 };
        tb.d[1] = { Wte, WTEt, 1536, 768, 768, 288 };
        k_wtr<<<576, 256, 0, stream>>>(tb);
    }
    // bias-init hs/ts/pb in one pass (contiguous), then atomic k-split GEMMs (raw, tanh at consumers)
    k_binit3<<<(3*Mr*Hn)/256, 256, 0, stream>>>(bhe, bte, bbl, ws + o_HS);
    k_gmfma<1,0><<<dim3(24,12,3), 256, 0, stream>>>(ws + oSH, ws + oRS, nul, Hn, Hn, 0,
        WHEt, nul, ws + o_HS, nulw, nulw, Mr, Hn, 512, 0, 0, 0);
    k_gmfma<1,0><<<dim3(24,12,3), 256, 0, stream>>>(ws + oST, ws + oRS, nul, Hn, Hn, 0,
        WTEt, nul, ws + o_TS, nulw, nulw, Mr, Hn, 512, 0, 0, 0);

    // bilinear: Wbl transpose (all X dead), MFMA v8
    {
        WT8 tb{}; tb.nd = 1;
        tb.d[0] = { Wbl, WBLt, 49152, 768, 768, 0 };
        k_wtr<<<9216, 256, 0, stream>>>(tb);
    }
    k_blmfma<<<dim3(24,12,6), 256, 0, stream>>>(ws + o_HS, ws + o_TS, WBLt, ws + o_PB);

    k_featpp<<<Mr, 256, 0, stream>>>(ws + o_PB, pos, hts, ws + oFP);

    // late weight transposes (WblT dead)
    {
        WT8 tb{}; tb.nd = 6;
        tb.d[0] = { Wpp, WPPt, 1024, 768, 768, 0 };
        tb.d[1] = { Wgq, WGQt, 768, 768, 768, 192 };
        tb.d[2] = { Wgk, (unsigned short*)(ws + oWGK), 768, 768, 768, 336 };
        tb.d[3] = { Wgv, (unsigned short*)(ws + oWGV), 768, 768, 768, 480 };
        tb.d[4] = { Wp1, WP1t, 2304, 768, 768, 624 };
        tb.d[5] = { Wp2, WP2t, 768, 97, 128, 1056 };
        k_wtr<<<1080, 256, 0, stream>>>(tb);
    }
    // pairT-acc = fpp @ Wpp + bpp  (raw; tanh at consumers)
    k_binit<<<(Mr*Hn)/256, 256, 0, stream>>>(bpp, ws + oPT, Hn);
    k_gmfma<1,0><<<dim3(24,12,2), 256, 0, stream>>>(ws + oFP, nul, nul, 1024, 0, 0,
        WPPt, nul, ws + oPT, nulw, nulw, Mr, Hn, 512, 0, 0, 0);
    // zero Vt16 (pad cols 380..383 must be 0)
    k_fillu<<<2304, 256, 0, stream>>>((unsigned int*)Vt16, 0u, Bn*Hn*384/2);
    // fused q|K16|Vt16 = tanh(pairT) @ [Wgq|Wgk|Wgv]
    k_gmfma<16,1><<<dim3(24,36,1), 256, 0, stream>>>(ws + oPT, nul, nul, Hn, 0, 0,
        WGQt, nul, ws + oQ, (float*)K16, (float*)Vt16, Mr, 3*Hn, 0, 0, 0, 0);
    // S = q @ K16^T (batched, raw scores)
    k_gmfma<32,0><<<dim3(6,6,4), 256, 0, stream>>>(ws + oQ, nul, nul, Hn, 0, 0,
        K16, nul, ws + oP2, nulw, nulw, Pn, Pn, 0,
        (long)Pn*Hn, (long)Pn*Hn, (long)Pn*Pn);
    // masked softmax -> P f32 [b][380][384]
    k_smax<<<Mr, 256, 0, stream>>>(ws + oP2, vis, ws + oP_);
    // PV = P @ Vt16^T (batched) -> overwrite S region with PV
    k_gmfma<32,0><<<dim3(6,12,4), 256, 0, stream>>>(ws + oP_, nul, nul, 384, 0, 0,
        Vt16, nul, ws + oP2, nulw, nulw, Pn, Hn, 0,
        (long)Pn*384, (long)Hn*384, (long)Pn*Hn);
    // pair2 = tanh(pairT) + PV  (in place)
    k_resid<<<(Mr*Hn)/256, 256, 0, stream>>>(ws + oPT, ws + oP2);
    // t1-acc = [tanh(hs)|tanh(ts)|pair2] @ Wp1 + bp1  (raw; tanh at final gemm)
    k_binit<<<(Mr*Hn)/256, 256, 0, stream>>>(bp1, ws + oT1, Hn);
    k_gmfma<1,3><<<dim3(24,12,3), 256, 0, stream>>>(ws + o_HS, ws + o_TS, ws + oP2,
        Hn, Hn, Hn, WP1t, nul, ws + oT1, nulw, nulw, Mr, Hn, 768, 0, 0, 0);
    // logits = tanh(t1) @ Wp2 + bp2
    k_gmfma<4,1><<<dim3(24,2,1), 256, 0, stream>>>(ws + oT1, nul, nul, Hn, 0, 0,
        WP2t, bp2, out, nulw, nulw, Mr, 97, 0, 0, 0, 0);
}